// Round 4
// baseline (414.030 us; speedup 1.0000x reference)
//
#include <hip/hip_runtime.h>

#define B_ 4
#define T_ 1024
#define D_ 512
#define H_ 8
#define DH_ 64
#define L_ 2047

typedef __attribute__((ext_vector_type(8))) short bf16x8;
typedef __attribute__((ext_vector_type(4))) float f32x4;
typedef __attribute__((ext_vector_type(8))) unsigned short us8v;
typedef __attribute__((ext_vector_type(4))) unsigned short us4v;

__device__ __forceinline__ void split_bf16(float a, unsigned short& h, unsigned short& l) {
  unsigned u = __float_as_uint(a);
  h = (unsigned short)(u >> 16);
  float hf = __uint_as_float(u & 0xFFFF0000u);
  l = (unsigned short)(__float_as_uint(a - hf) >> 16);
}
__device__ __forceinline__ float bf2f(unsigned short s) {
  return __uint_as_float(((unsigned)s) << 16);
}

// ---------------------------------------------------------------------------
// Flat split: x (2048 blocks) + pos_emb (1024 blocks, guarded tail).
// ---------------------------------------------------------------------------
__global__ __launch_bounds__(256)
void conv_flat(const float* __restrict__ x, unsigned short* __restrict__ xh,
               unsigned short* __restrict__ xl,
               const float* __restrict__ p, unsigned short* __restrict__ ph,
               unsigned short* __restrict__ pl) {
  int blk = blockIdx.x;
  const float* in; unsigned short* oh; unsigned short* ol; long n, base;
  if (blk < 2048) { in = x; oh = xh; ol = xl; n = 2097152; base = (long)blk * 1024; }
  else { in = p; oh = ph; ol = pl; n = 1048064; base = (long)(blk - 2048) * 1024; }
  long i = base + threadIdx.x * 4;
  if (i + 4 <= n) {
    float4 a = *(const float4*)&in[i];
    us4v h, l; unsigned short th, tl;
    split_bf16(a.x, th, tl); h[0] = th; l[0] = tl;
    split_bf16(a.y, th, tl); h[1] = th; l[1] = tl;
    split_bf16(a.z, th, tl); h[2] = th; l[2] = tl;
    split_bf16(a.w, th, tl); h[3] = th; l[3] = tl;
    *(us4v*)&oh[i] = h; *(us4v*)&ol[i] = l;
  } else {
    for (long e = i; e < n; ++e) {
      unsigned short th, tl; split_bf16(in[e], th, tl); oh[e] = th; ol[e] = tl;
    }
  }
}

// ---------------------------------------------------------------------------
// Weight split + transpose: W[k][n] fp32 -> Wt_h/Wt_l [n][k] bf16.
// z selects among the 5 weight matrices (Wq,Wk,Wv,Wr,Wo).
// ---------------------------------------------------------------------------
__global__ __launch_bounds__(256)
void conv_wt(const float* w0, const float* w1, const float* w2, const float* w3,
             const float* w4, unsigned short* __restrict__ wth,
             unsigned short* __restrict__ wtl) {
  const float* W = blockIdx.z == 0 ? w0 : blockIdx.z == 1 ? w1 :
                   blockIdx.z == 2 ? w2 : blockIdx.z == 3 ? w3 : w4;
  unsigned short* oh = wth + (long)blockIdx.z * 262144;
  unsigned short* ol = wtl + (long)blockIdx.z * 262144;
  __shared__ unsigned short Th[64][72], Tl[64][72];
  const int k0 = blockIdx.x * 64, n0 = blockIdx.y * 64;
  const int tid = threadIdx.x;
#pragma unroll
  for (int m = 0; m < 4; ++m) {
    int s = tid + 256 * m;
    int kk = s >> 4, n4 = (s & 15) * 4;
    float4 a = *(const float4*)&W[(long)(k0 + kk) * 512 + n0 + n4];
    unsigned short th, tl;
    split_bf16(a.x, th, tl); Th[n4 + 0][kk] = th; Tl[n4 + 0][kk] = tl;
    split_bf16(a.y, th, tl); Th[n4 + 1][kk] = th; Tl[n4 + 1][kk] = tl;
    split_bf16(a.z, th, tl); Th[n4 + 2][kk] = th; Tl[n4 + 2][kk] = tl;
    split_bf16(a.w, th, tl); Th[n4 + 3][kk] = th; Tl[n4 + 3][kk] = tl;
  }
  __syncthreads();
#pragma unroll
  for (int m = 0; m < 2; ++m) {
    int s = tid + 256 * m;
    int nn = s >> 3, kb = (s & 7) * 8;
    *(us8v*)&oh[(long)(n0 + nn) * 512 + k0 + kb] = *(const us8v*)&Th[nn][kb];
    *(us8v*)&ol[(long)(n0 + nn) * 512 + k0 + kb] = *(const us8v*)&Tl[nn][kb];
  }
}

// ---------------------------------------------------------------------------
// Split-bf16 MFMA GEMM v2: C[M,512] = A @ W (+bias), A pre-split, W pre-split
// AND pre-transposed ([n][k]). BM=128 BN=128 BK=64, 256 thr / 4 waves (2x2),
// wave tile 64x64. Epilogues: ep0 fp32, ep1 split-pair, ep2 split transposed
// to Vt[b][h][d][token] (via LDS transpose).
// ---------------------------------------------------------------------------
struct EpCfg {
  const unsigned short* wth;
  const unsigned short* wtl;
  const float* bias;
  float* cf;
  unsigned short* ch;
  unsigned short* cl;
  int ep;
};

__global__ __launch_bounds__(256)
void gemm2(const unsigned short* __restrict__ Ag_h, const unsigned short* __restrict__ Ag_l,
           EpCfg e0, EpCfg e1, EpCfg e2, int mlimit) {
  __shared__ unsigned short SMEM[4 * 128 * 68];
  unsigned short (*Ah)[68] = (unsigned short (*)[68])&SMEM[0];
  unsigned short (*Al)[68] = (unsigned short (*)[68])&SMEM[128 * 68];
  unsigned short (*Bh)[68] = (unsigned short (*)[68])&SMEM[2 * 128 * 68];
  unsigned short (*Bl)[68] = (unsigned short (*)[68])&SMEM[3 * 128 * 68];

  const int tid = threadIdx.x;
  const int row0 = blockIdx.x * 128;
  const int cg0 = blockIdx.y * 128;
  const int wsel = cg0 >> 9;
  const int col0 = cg0 & 511;
  const EpCfg C = wsel == 0 ? e0 : (wsel == 1 ? e1 : e2);

  const int lane = tid & 63;
  const int w = tid >> 6;
  const int wr = (w >> 1) * 64;
  const int wc = (w & 1) * 64;
  const int frow = lane & 15;
  const int fk8 = (lane >> 4) * 8;

  f32x4 acc[4][4];
#pragma unroll
  for (int a = 0; a < 4; ++a)
#pragma unroll
    for (int bb = 0; bb < 4; ++bb) acc[a][bb] = (f32x4){0.f, 0.f, 0.f, 0.f};

  for (int k0 = 0; k0 < 512; k0 += 64) {
#pragma unroll
    for (int m = 0; m < 4; ++m) {
      int s = tid + 256 * m;
      int rr = s >> 3, kb = (s & 7) * 8;
      int gr = min(row0 + rr, mlimit - 1);
      long gi = (long)gr * 512 + k0 + kb;
      *(us8v*)&Ah[rr][kb] = *(const us8v*)&Ag_h[gi];
      *(us8v*)&Al[rr][kb] = *(const us8v*)&Ag_l[gi];
    }
#pragma unroll
    for (int m = 0; m < 4; ++m) {
      int s = tid + 256 * m;
      int nn = s >> 3, kb = (s & 7) * 8;
      long gi = (long)(col0 + nn) * 512 + k0 + kb;
      *(us8v*)&Bh[nn][kb] = *(const us8v*)&C.wth[gi];
      *(us8v*)&Bl[nn][kb] = *(const us8v*)&C.wtl[gi];
    }
    __syncthreads();
#pragma unroll
    for (int ks = 0; ks < 2; ++ks) {
      bf16x8 bh[4], bl[4];
#pragma unroll
      for (int bb = 0; bb < 4; ++bb) {
        bh[bb] = *(const bf16x8*)&Bh[wc + bb * 16 + frow][ks * 32 + fk8];
        bl[bb] = *(const bf16x8*)&Bl[wc + bb * 16 + frow][ks * 32 + fk8];
      }
#pragma unroll
      for (int a = 0; a < 4; ++a) {
        bf16x8 ah = *(const bf16x8*)&Ah[wr + a * 16 + frow][ks * 32 + fk8];
        bf16x8 al = *(const bf16x8*)&Al[wr + a * 16 + frow][ks * 32 + fk8];
#pragma unroll
        for (int bb = 0; bb < 4; ++bb) {
          acc[a][bb] = __builtin_amdgcn_mfma_f32_16x16x32_bf16(ah, bh[bb], acc[a][bb], 0, 0, 0);
          acc[a][bb] = __builtin_amdgcn_mfma_f32_16x16x32_bf16(ah, bl[bb], acc[a][bb], 0, 0, 0);
          acc[a][bb] = __builtin_amdgcn_mfma_f32_16x16x32_bf16(al, bh[bb], acc[a][bb], 0, 0, 0);
        }
      }
    }
    __syncthreads();
  }

  const int lg4 = (lane >> 4) * 4;
  if (C.ep <= 1) {
#pragma unroll
    for (int bb = 0; bb < 4; ++bb) {
      int col = col0 + wc + bb * 16 + frow;
      float bv = C.bias ? C.bias[col] : 0.f;
#pragma unroll
      for (int a = 0; a < 4; ++a) {
#pragma unroll
        for (int g = 0; g < 4; ++g) {
          int row = row0 + wr + a * 16 + lg4 + g;
          if (row >= mlimit) continue;
          long idx = (long)row * 512 + col;
          float val = acc[a][bb][g] + bv;
          if (C.ep == 0) C.cf[idx] = val;
          else {
            unsigned short th, tl; split_bf16(val, th, tl);
            C.ch[idx] = th; C.cl[idx] = tl;
          }
        }
      }
    }
  } else {
    // Vt epilogue: transpose tile via LDS, then coalesced us8v writes.
    unsigned short (*Th)[136] = (unsigned short (*)[136])&SMEM[0];
    unsigned short (*Tl)[136] = (unsigned short (*)[136])&SMEM[2 * 128 * 68];
#pragma unroll
    for (int bb = 0; bb < 4; ++bb) {
      int clx = wc + bb * 16 + frow;
      float bv = C.bias ? C.bias[col0 + clx] : 0.f;
#pragma unroll
      for (int a = 0; a < 4; ++a) {
#pragma unroll
        for (int g = 0; g < 4; ++g) {
          int rlx = wr + a * 16 + lg4 + g;
          unsigned short th, tl;
          split_bf16(acc[a][bb][g] + bv, th, tl);
          Th[clx][rlx] = th; Tl[clx][rlx] = tl;
        }
      }
    }
    __syncthreads();
    int bbat = row0 >> 10, tok0 = row0 & 1023;
#pragma unroll
    for (int m = 0; m < 8; ++m) {
      int s = tid + 256 * m;
      int dd = s >> 4, tb = (s & 15) * 8;
      int colg = col0 + dd;
      long gi = (((long)bbat * 8 + (colg >> 6)) * 64 + (colg & 63)) * 1024 + tok0 + tb;
      *(us8v*)&C.ch[gi] = *(const us8v*)&Th[dd][tb];
      *(us8v*)&C.cl[gi] = *(const us8v*)&Tl[dd][tb];
    }
  }
}

// ---------------------------------------------------------------------------
// uk[b,h,t] = u[h]·k[b,t,h,:], vr[h,l] = v[h]·r[l,h,:]. One wave per row;
// wave loads the full 512-short row coalesced, 8-lane groups own one head.
// ---------------------------------------------------------------------------
__global__ __launch_bounds__(256)
void ukvr_kernel(const unsigned short* __restrict__ kh, const unsigned short* __restrict__ kl,
                 const unsigned short* __restrict__ rh, const unsigned short* __restrict__ rl,
                 const float* __restrict__ u, const float* __restrict__ v,
                 float* __restrict__ uk, float* __restrict__ vr) {
  int wg = (blockIdx.x * 256 + threadIdx.x) >> 6;
  int lane = threadIdx.x & 63;
  int hh = lane >> 3;
  int d8 = (lane & 7) * 8;
  bool isuk = wg < 4096;
  const unsigned short* sh; const unsigned short* sl; const float* cf; long row;
  if (isuk) { sh = kh; sl = kl; cf = u; row = wg; }
  else { sh = rh; sl = rl; cf = v; row = min(wg - 4096, L_ - 1); }
  long gi = row * 512 + hh * 64 + d8;
  us8v ah = *(const us8v*)&sh[gi];
  us8v al = *(const us8v*)&sl[gi];
  float part = 0.f;
#pragma unroll
  for (int e = 0; e < 8; ++e)
    part += cf[hh * 64 + d8 + e] * (bf2f(ah[e]) + bf2f(al[e]));
  part += __shfl_xor(part, 1);
  part += __shfl_xor(part, 2);
  part += __shfl_xor(part, 4);
  if ((lane & 7) == 0) {
    if (isuk) uk[(wg >> 10) * 8192 + hh * 1024 + (wg & 1023)] = part;
    else vr[hh * 2048 + (wg - 4096)] = part;
  }
}

// ---------------------------------------------------------------------------
// Fused rel-pos attention, split-bf16 MFMA v2.
// scores = q·k + q·r_shift + uk[j] + vr_shift  (uk/vr precomputed fp32).
// Shift-gather done in-register via __shfl (no band buffer, no extra barrier).
// RW ring buffer (3x64 rows); V arrives pre-transposed; 2 barriers/iter.
// ---------------------------------------------------------------------------
__global__ __launch_bounds__(512)
void attn_mfma2(const unsigned short* __restrict__ qhp, const unsigned short* __restrict__ qlp,
                const unsigned short* __restrict__ kh, const unsigned short* __restrict__ kl,
                const unsigned short* __restrict__ vth, const unsigned short* __restrict__ vtl,
                const unsigned short* __restrict__ rh, const unsigned short* __restrict__ rl,
                const float* __restrict__ uk, const float* __restrict__ vr,
                unsigned short* __restrict__ oh, unsigned short* __restrict__ ol) {
  const int qt = blockIdx.x, h = blockIdx.y, b = blockIdx.z;
  const int q0 = qt * 128;
  const int tid = threadIdx.x;
  const int lane = tid & 63;
  const int wid = tid >> 6;
  const int lr = lane & 15;
  const int lg = lane >> 4;

  __shared__ unsigned short Kh[64][68], Kl[64][68];
  __shared__ unsigned short Vh[64][68], Vl[64][68];
  __shared__ unsigned short RWh[192][68], RWl[192][68];
  __shared__ unsigned short Ph[128][68], Pl[128][68];

  bf16x8 quh[2], qul[2];
  {
    long qoff = (long)(b * T_ + q0 + wid * 16 + lr) * 512 + h * 64 + lg * 8;
    quh[0] = *(const bf16x8*)&qhp[qoff];
    quh[1] = *(const bf16x8*)&qhp[qoff + 32];
    qul[0] = *(const bf16x8*)&qlp[qoff];
    qul[1] = *(const bf16x8*)&qlp[qoff + 32];
  }

  f32x4 pv[4];
#pragma unroll
  for (int c = 0; c < 4; ++c) pv[c] = (f32x4){0.f, 0.f, 0.f, 0.f};
  float m_run[4], l_run[4];
#pragma unroll
  for (int r = 0; r < 4; ++r) { m_run[r] = -3.0e38f; l_run[r] = 0.f; }

  const int band0 = 112 - wid * 16;
  const int sbase0 = 14 - 2 * qt;       // first window segment (abs/64)
  const float* ukrow = uk + ((long)b * 8 + h) * 1024;
  const float* vrrow = vr + (long)h * 2048;
  const int stj = tid >> 3;
  const int std8 = (tid & 7) * 8;

  for (int t = 0; t < 16; ++t) {
    const int j0 = t * 64;
    __syncthreads();   // previous iter's LDS reads complete

    { long gi = (long)(b * T_ + j0 + stj) * 512 + h * 64 + std8;
      *(us8v*)&Kh[stj][std8] = *(const us8v*)&kh[gi];
      *(us8v*)&Kl[stj][std8] = *(const us8v*)&kl[gi]; }
    { long gi = (((long)b * 8 + h) * 64 + stj) * 1024 + j0 + std8;
      *(us8v*)&Vh[stj][std8] = *(const us8v*)&vth[gi];
      *(us8v*)&Vl[stj][std8] = *(const us8v*)&vtl[gi]; }
    if (t == 0) {
#pragma unroll
      for (int ss = 0; ss < 2; ++ss) {
        int seg = sbase0 + ss;
        int slot = seg % 3;
        long A = min(seg * 64 + stj, L_ - 1);
        long gi = A * 512 + h * 64 + std8;
        *(us8v*)&RWh[slot * 64 + stj][std8] = *(const us8v*)&rh[gi];
        *(us8v*)&RWl[slot * 64 + stj][std8] = *(const us8v*)&rl[gi];
      }
    }
    { int seg = sbase0 + t + 2;
      int slot = seg % 3;
      long A = min(seg * 64 + stj, L_ - 1);
      long gi = A * 512 + h * 64 + std8;
      *(us8v*)&RWh[slot * 64 + stj][std8] = *(const us8v*)&rh[gi];
      *(us8v*)&RWl[slot * 64 + stj][std8] = *(const us8v*)&rl[gi]; }
    __syncthreads();

    f32x4 ac[4], bda[5];
#pragma unroll
    for (int c = 0; c < 4; ++c) ac[c] = (f32x4){0.f, 0.f, 0.f, 0.f};
#pragma unroll
    for (int c = 0; c < 5; ++c) bda[c] = (f32x4){0.f, 0.f, 0.f, 0.f};

#pragma unroll
    for (int ks = 0; ks < 2; ++ks) {
#pragma unroll
      for (int c = 0; c < 4; ++c) {
        bf16x8 kbh = *(const bf16x8*)&Kh[c * 16 + lr][ks * 32 + lg * 8];
        bf16x8 kbl = *(const bf16x8*)&Kl[c * 16 + lr][ks * 32 + lg * 8];
        ac[c] = __builtin_amdgcn_mfma_f32_16x16x32_bf16(quh[ks], kbh, ac[c], 0, 0, 0);
        ac[c] = __builtin_amdgcn_mfma_f32_16x16x32_bf16(quh[ks], kbl, ac[c], 0, 0, 0);
        ac[c] = __builtin_amdgcn_mfma_f32_16x16x32_bf16(qul[ks], kbh, ac[c], 0, 0, 0);
      }
#pragma unroll
      for (int c = 0; c < 5; ++c) {
        int off = band0 + c * 16;
        int slot = (sbase0 + t + (off >> 6)) % 3;
        int rrow = slot * 64 + (off & 63) + lr;
        bf16x8 rbh = *(const bf16x8*)&RWh[rrow][ks * 32 + lg * 8];
        bf16x8 rbl = *(const bf16x8*)&RWl[rrow][ks * 32 + lg * 8];
        bda[c] = __builtin_amdgcn_mfma_f32_16x16x32_bf16(quh[ks], rbh, bda[c], 0, 0, 0);
        bda[c] = __builtin_amdgcn_mfma_f32_16x16x32_bf16(quh[ks], rbl, bda[c], 0, 0, 0);
        bda[c] = __builtin_amdgcn_mfma_f32_16x16x32_bf16(qul[ks], rbh, bda[c], 0, 0, 0);
      }
    }

    // fold vr (column-only) into BD' pre-gather
    const int wbase = 896 - q0 + j0;
#pragma unroll
    for (int c = 0; c < 5; ++c) {
      float vv = vrrow[wbase + band0 + c * 16 + lr];
#pragma unroll
      for (int r = 0; r < 4; ++r) bda[c][r] += vv;
    }

    // in-register rel-shift gather via shfl, then scores
    float p_[4][4];
#pragma unroll
    for (int r = 0; r < 4; ++r) {
      int rowl = lg * 4 + r;
      int e = lr - rowl + 15;          // in [0,30]
      int srcl = lg * 16 + (e & 15);
      int carry = e >> 4;
      float s0 = __shfl(bda[0][r], srcl);
      float s1 = __shfl(bda[1][r], srcl);
      float s2 = __shfl(bda[2][r], srcl);
      float s3 = __shfl(bda[3][r], srcl);
      float s4 = __shfl(bda[4][r], srcl);
      p_[0][r] = carry ? s1 : s0;
      p_[1][r] = carry ? s2 : s1;
      p_[2][r] = carry ? s3 : s2;
      p_[3][r] = carry ? s4 : s3;
    }
#pragma unroll
    for (int c = 0; c < 4; ++c) {
      float ukv = ukrow[j0 + c * 16 + lr];
#pragma unroll
      for (int r = 0; r < 4; ++r)
        p_[c][r] = (ac[c][r] + p_[c][r] + ukv) * 0.125f;
    }

    // online softmax (rows = lg*4+r across 16 lr lanes)
#pragma unroll
    for (int r = 0; r < 4; ++r) {
      float lm = fmaxf(fmaxf(p_[0][r], p_[1][r]), fmaxf(p_[2][r], p_[3][r]));
#pragma unroll
      for (int off = 1; off < 16; off <<= 1)
        lm = fmaxf(lm, __shfl_xor(lm, off));
      float mnew = fmaxf(m_run[r], lm);
      float rescale = __expf(m_run[r] - mnew);
      float srow = 0.f;
#pragma unroll
      for (int c = 0; c < 4; ++c) {
        float pe = __expf(p_[c][r] - mnew);
        p_[c][r] = pe;
        srow += pe;
      }
#pragma unroll
      for (int off = 1; off < 16; off <<= 1)
        srow += __shfl_xor(srow, off);
      l_run[r] = l_run[r] * rescale + srow;
      m_run[r] = mnew;
#pragma unroll
      for (int c = 0; c < 4; ++c) pv[c][r] *= rescale;
    }

    // P split -> LDS (wave-private rows; conflict-free at stride 68)
#pragma unroll
    for (int c = 0; c < 4; ++c)
#pragma unroll
      for (int r = 0; r < 4; ++r) {
        unsigned short th, tl;
        split_bf16(p_[c][r], th, tl);
        Ph[wid * 16 + lg * 4 + r][c * 16 + lr] = th;
        Pl[wid * 16 + lg * 4 + r][c * 16 + lr] = tl;
      }

    // PV
#pragma unroll
    for (int ks = 0; ks < 2; ++ks) {
      bf16x8 pah = *(const bf16x8*)&Ph[wid * 16 + lr][ks * 32 + lg * 8];
      bf16x8 pal = *(const bf16x8*)&Pl[wid * 16 + lr][ks * 32 + lg * 8];
#pragma unroll
      for (int c = 0; c < 4; ++c) {
        bf16x8 vbh = *(const bf16x8*)&Vh[c * 16 + lr][ks * 32 + lg * 8];
        bf16x8 vbl = *(const bf16x8*)&Vl[c * 16 + lr][ks * 32 + lg * 8];
        pv[c] = __builtin_amdgcn_mfma_f32_16x16x32_bf16(pah, vbh, pv[c], 0, 0, 0);
        pv[c] = __builtin_amdgcn_mfma_f32_16x16x32_bf16(pah, vbl, pv[c], 0, 0, 0);
        pv[c] = __builtin_amdgcn_mfma_f32_16x16x32_bf16(pal, vbh, pv[c], 0, 0, 0);
      }
    }
  }

  // epilogue: normalize, split, store [B,T,H,DH]
#pragma unroll
  for (int r = 0; r < 4; ++r) {
    float inv = 1.f / l_run[r];
    long base = (long)(b * T_ + q0 + wid * 16 + lg * 4 + r) * 512 + h * 64;
#pragma unroll
    for (int c = 0; c < 4; ++c) {
      unsigned short th, tl;
      split_bf16(pv[c][r] * inv, th, tl);
      oh[base + c * 16 + lr] = th;
      ol[base + c * 16 + lr] = tl;
    }
  }
}

// ---------------------------------------------------------------------------
extern "C" void kernel_launch(void* const* d_in, const int* in_sizes, int n_in,
                              void* d_out, int out_size, void* d_ws, size_t ws_size,
                              hipStream_t stream) {
  const float* x       = (const float*)d_in[0];
  const float* pos_emb = (const float*)d_in[1];
  const float* Wq      = (const float*)d_in[2];
  const float* bq      = (const float*)d_in[3];
  const float* Wk      = (const float*)d_in[4];
  const float* bk      = (const float*)d_in[5];
  const float* Wv      = (const float*)d_in[6];
  const float* bv      = (const float*)d_in[7];
  const float* Wr      = (const float*)d_in[8];
  const float* Wo      = (const float*)d_in[9];
  const float* bo      = (const float*)d_in[10];
  const float* u       = (const float*)d_in[11];
  const float* v       = (const float*)d_in[12];

  float* out = (float*)d_out;
  unsigned short* us = (unsigned short*)d_ws;
  const long S = 2097152;   // MT * D

  unsigned short* qh  = us;
  unsigned short* ql  = us + S;
  unsigned short* kh  = us + 2 * S;
  unsigned short* kl  = us + 3 * S;
  unsigned short* vth = us + 4 * S;
  unsigned short* vtl = us + 5 * S;
  unsigned short* rh  = us + 6 * S;              // 2048*512
  unsigned short* rl  = rh + 1048576;
  unsigned short* xh  = us + 7 * S;              // -> atth after QKV
  unsigned short* xl  = us + 8 * S;
  unsigned short* ph  = us + 9 * S;              // pos split, 2048*512
  unsigned short* pl  = ph + 1048576;
  unsigned short* wth = us + 10 * S;             // 5 x 262144
  unsigned short* wtl = wth + 1310720;
  float* uk = (float*)(wtl + 1310720);           // [4][8][1024]
  float* vr = uk + 32768;                        // [8][2048]

  conv_flat<<<3072, 256, 0, stream>>>(x, xh, xl, pos_emb, ph, pl);
  conv_wt<<<dim3(8, 8, 5), 256, 0, stream>>>(Wq, Wk, Wv, Wr, Wo, wth, wtl);

  EpCfg cq{wth,            wtl,            bq,      nullptr, qh,  ql,  1};
  EpCfg ck{wth + 262144,   wtl + 262144,   bk,      nullptr, kh,  kl,  1};
  EpCfg cv{wth + 524288,   wtl + 524288,   bv,      nullptr, vth, vtl, 2};
  gemm2<<<dim3(32, 12), 256, 0, stream>>>(xh, xl, cq, ck, cv, 4096);

  EpCfg cr{wth + 786432,   wtl + 786432,   nullptr, nullptr, rh,  rl,  1};
  gemm2<<<dim3(16, 4), 256, 0, stream>>>(ph, pl, cr, cr, cr, 2047);

  ukvr_kernel<<<1536, 256, 0, stream>>>(kh, kl, rh, rl, u, v, uk, vr);

  attn_mfma2<<<dim3(8, 8, 4), 512, 0, stream>>>(qh, ql, kh, kl, vth, vtl, rh, rl,
                                                uk, vr, xh, xl);

  EpCfg co{wth + 1048576,  wtl + 1048576,  bo,      out,     nullptr, nullptr, 0};
  gemm2<<<dim3(32, 4), 256, 0, stream>>>(xh, xl, co, co, co, 4096);
}

// Round 6
// 383.188 us; speedup vs baseline: 1.0805x; 1.0805x over previous
//
#include <hip/hip_runtime.h>

#define B_ 4
#define T_ 1024
#define D_ 512
#define H_ 8
#define DH_ 64
#define L_ 2047

typedef __attribute__((ext_vector_type(8))) short bf16x8;
typedef __attribute__((ext_vector_type(4))) float f32x4;
typedef __attribute__((ext_vector_type(8))) unsigned short us8v;
typedef __attribute__((ext_vector_type(4))) unsigned short us4v;

__device__ __forceinline__ void split_bf16(float a, unsigned short& h, unsigned short& l) {
  unsigned u = __float_as_uint(a);
  h = (unsigned short)(u >> 16);
  float hf = __uint_as_float(u & 0xFFFF0000u);
  l = (unsigned short)(__float_as_uint(a - hf) >> 16);
}
__device__ __forceinline__ float bf2f(unsigned short s) {
  return __uint_as_float(((unsigned)s) << 16);
}

// ---------------------------------------------------------------------------
// Flat split: x (2048 blocks) + pos_emb (1024 blocks, guarded tail).
// ---------------------------------------------------------------------------
__global__ __launch_bounds__(256)
void conv_flat(const float* __restrict__ x, unsigned short* __restrict__ xh,
               unsigned short* __restrict__ xl,
               const float* __restrict__ p, unsigned short* __restrict__ ph,
               unsigned short* __restrict__ pl) {
  int blk = blockIdx.x;
  const float* in; unsigned short* oh; unsigned short* ol; long n, base;
  if (blk < 2048) { in = x; oh = xh; ol = xl; n = 2097152; base = (long)blk * 1024; }
  else { in = p; oh = ph; ol = pl; n = 1048064; base = (long)(blk - 2048) * 1024; }
  long i = base + threadIdx.x * 4;
  if (i + 4 <= n) {
    float4 a = *(const float4*)&in[i];
    us4v h, l; unsigned short th, tl;
    split_bf16(a.x, th, tl); h[0] = th; l[0] = tl;
    split_bf16(a.y, th, tl); h[1] = th; l[1] = tl;
    split_bf16(a.z, th, tl); h[2] = th; l[2] = tl;
    split_bf16(a.w, th, tl); h[3] = th; l[3] = tl;
    *(us4v*)&oh[i] = h; *(us4v*)&ol[i] = l;
  } else {
    for (long e = i; e < n; ++e) {
      unsigned short th, tl; split_bf16(in[e], th, tl); oh[e] = th; ol[e] = tl;
    }
  }
}

// ---------------------------------------------------------------------------
// Weight split + transpose: W[k][n] fp32 -> Wt_h/Wt_l [n][k] bf16.
// ---------------------------------------------------------------------------
__global__ __launch_bounds__(256)
void conv_wt(const float* w0, const float* w1, const float* w2, const float* w3,
             const float* w4, unsigned short* __restrict__ wth,
             unsigned short* __restrict__ wtl) {
  const float* W = blockIdx.z == 0 ? w0 : blockIdx.z == 1 ? w1 :
                   blockIdx.z == 2 ? w2 : blockIdx.z == 3 ? w3 : w4;
  unsigned short* oh = wth + (long)blockIdx.z * 262144;
  unsigned short* ol = wtl + (long)blockIdx.z * 262144;
  __shared__ unsigned short Th[64][72], Tl[64][72];
  const int k0 = blockIdx.x * 64, n0 = blockIdx.y * 64;
  const int tid = threadIdx.x;
#pragma unroll
  for (int m = 0; m < 4; ++m) {
    int s = tid + 256 * m;
    int kk = s >> 4, n4 = (s & 15) * 4;
    float4 a = *(const float4*)&W[(long)(k0 + kk) * 512 + n0 + n4];
    unsigned short th, tl;
    split_bf16(a.x, th, tl); Th[n4 + 0][kk] = th; Tl[n4 + 0][kk] = tl;
    split_bf16(a.y, th, tl); Th[n4 + 1][kk] = th; Tl[n4 + 1][kk] = tl;
    split_bf16(a.z, th, tl); Th[n4 + 2][kk] = th; Tl[n4 + 2][kk] = tl;
    split_bf16(a.w, th, tl); Th[n4 + 3][kk] = th; Tl[n4 + 3][kk] = tl;
  }
  __syncthreads();
#pragma unroll
  for (int m = 0; m < 2; ++m) {
    int s = tid + 256 * m;
    int nn = s >> 3, kb = (s & 7) * 8;
    *(us8v*)&oh[(long)(n0 + nn) * 512 + k0 + kb] = *(const us8v*)&Th[nn][kb];
    *(us8v*)&ol[(long)(n0 + nn) * 512 + k0 + kb] = *(const us8v*)&Tl[nn][kb];
  }
}

// ---------------------------------------------------------------------------
// Split-bf16 MFMA GEMM v3: C[M,512] = A @ W (+bias).
// BM=128 BN=128 BK=32, 256 thr / 4 waves (2x2), wave tile 64x64.
// LDS 36 KB -> up to 4 blocks/CU (reg-limited ~3). Epilogues:
//   ep0: fp32 direct (64B segments)
//   ep1: split-pair, LDS-bounced in two 64-row passes, us8v coalesced stores
//   ep2: split-pair transposed to Vt[b][h][d][token], two 64-col passes
// ---------------------------------------------------------------------------
struct EpCfg {
  const unsigned short* wth;
  const unsigned short* wtl;
  const float* bias;
  float* cf;
  unsigned short* ch;
  unsigned short* cl;
  int ep;
};

__global__ __launch_bounds__(256)
void gemm3(const unsigned short* __restrict__ Ag_h, const unsigned short* __restrict__ Ag_l,
           EpCfg e0, EpCfg e1, EpCfg e2, int mlimit) {
  __shared__ unsigned short SMEM[18432];   // 36864 B
  unsigned short (*Ah)[36] = (unsigned short (*)[36])&SMEM[0];      // 128x36
  unsigned short (*Al)[36] = (unsigned short (*)[36])&SMEM[4608];
  unsigned short (*Bh)[36] = (unsigned short (*)[36])&SMEM[9216];
  unsigned short (*Bl)[36] = (unsigned short (*)[36])&SMEM[13824];

  const int tid = threadIdx.x;
  const int row0 = blockIdx.x * 128;
  const int cg0 = blockIdx.y * 128;
  const int wsel = cg0 >> 9;
  const int col0 = cg0 & 511;
  const EpCfg C = wsel == 0 ? e0 : (wsel == 1 ? e1 : e2);

  const int lane = tid & 63;
  const int w = tid >> 6;
  const int wr = (w >> 1) * 64;
  const int wc = (w & 1) * 64;
  const int frow = lane & 15;
  const int fk8 = (lane >> 4) * 8;

  // staging map: 2 slots per array per thread
  const int strow = tid >> 2;            // 0..63  (+64 on second slot)
  const int stkb = (tid & 3) * 8;        // 0..24

  f32x4 acc[4][4];
#pragma unroll
  for (int a = 0; a < 4; ++a)
#pragma unroll
    for (int bb = 0; bb < 4; ++bb) acc[a][bb] = (f32x4){0.f, 0.f, 0.f, 0.f};

  for (int k0 = 0; k0 < 512; k0 += 32) {
#pragma unroll
    for (int m = 0; m < 2; ++m) {
      int rr = strow + m * 64;
      int gr = min(row0 + rr, mlimit - 1);
      long gi = (long)gr * 512 + k0 + stkb;
      *(us8v*)&Ah[rr][stkb] = *(const us8v*)&Ag_h[gi];
      *(us8v*)&Al[rr][stkb] = *(const us8v*)&Ag_l[gi];
      long bi = (long)(col0 + rr) * 512 + k0 + stkb;
      *(us8v*)&Bh[rr][stkb] = *(const us8v*)&C.wth[bi];
      *(us8v*)&Bl[rr][stkb] = *(const us8v*)&C.wtl[bi];
    }
    __syncthreads();

    bf16x8 bhf[4], blf[4];
#pragma unroll
    for (int bb = 0; bb < 4; ++bb) {
      bhf[bb] = *(const bf16x8*)&Bh[wc + bb * 16 + frow][fk8];
      blf[bb] = *(const bf16x8*)&Bl[wc + bb * 16 + frow][fk8];
    }
#pragma unroll
    for (int a = 0; a < 4; ++a) {
      bf16x8 ah = *(const bf16x8*)&Ah[wr + a * 16 + frow][fk8];
      bf16x8 al = *(const bf16x8*)&Al[wr + a * 16 + frow][fk8];
#pragma unroll
      for (int bb = 0; bb < 4; ++bb) {
        acc[a][bb] = __builtin_amdgcn_mfma_f32_16x16x32_bf16(ah, bhf[bb], acc[a][bb], 0, 0, 0);
        acc[a][bb] = __builtin_amdgcn_mfma_f32_16x16x32_bf16(ah, blf[bb], acc[a][bb], 0, 0, 0);
        acc[a][bb] = __builtin_amdgcn_mfma_f32_16x16x32_bf16(al, bhf[bb], acc[a][bb], 0, 0, 0);
      }
    }
    __syncthreads();
  }

  const int lg4 = (lane >> 4) * 4;

  if (C.ep == 0) {
    // fp32 direct: lanes 0-15 contiguous -> 64B segments
#pragma unroll
    for (int bb = 0; bb < 4; ++bb) {
      int col = col0 + wc + bb * 16 + frow;
      float bv = C.bias ? C.bias[col] : 0.f;
#pragma unroll
      for (int a = 0; a < 4; ++a) {
#pragma unroll
        for (int g = 0; g < 4; ++g) {
          int row = row0 + wr + a * 16 + lg4 + g;
          if (row < mlimit) C.cf[(long)row * 512 + col] = acc[a][bb][g] + bv;
        }
      }
    }
  } else if (C.ep == 1) {
    // split-pair bounced epilogue, two 64-row passes
    unsigned short (*Th)[136] = (unsigned short (*)[136])&SMEM[0];     // 64x136
    unsigned short (*Tl)[136] = (unsigned short (*)[136])&SMEM[8704];
#pragma unroll
    for (int p = 0; p < 2; ++p) {
      __syncthreads();
      if ((wr >> 6) == p) {
#pragma unroll
        for (int bb = 0; bb < 4; ++bb) {
          int clx = wc + bb * 16 + frow;
          float bv = C.bias ? C.bias[col0 + clx] : 0.f;
#pragma unroll
          for (int a = 0; a < 4; ++a) {
#pragma unroll
            for (int g = 0; g < 4; ++g) {
              unsigned short th, tl;
              split_bf16(acc[a][bb][g] + bv, th, tl);
              int rlx = a * 16 + lg4 + g;
              Th[rlx][clx] = th; Tl[rlx][clx] = tl;
            }
          }
        }
      }
      __syncthreads();
#pragma unroll
      for (int m = 0; m < 4; ++m) {
        int s = tid + 256 * m;
        int rr = s >> 4, cb = (s & 15) * 8;
        int row = row0 + p * 64 + rr;
        if (row < mlimit) {
          long gi = (long)row * 512 + col0 + cb;
          *(us8v*)&C.ch[gi] = *(const us8v*)&Th[rr][cb];
          *(us8v*)&C.cl[gi] = *(const us8v*)&Tl[rr][cb];
        }
      }
    }
  } else {
    // Vt epilogue: transpose to [b][h][d][token], two 64-col passes
    unsigned short (*Th)[136] = (unsigned short (*)[136])&SMEM[0];     // 64x136
    unsigned short (*Tl)[136] = (unsigned short (*)[136])&SMEM[8704];
    int bbat = row0 >> 10, tok0 = row0 & 1023;
#pragma unroll
    for (int p = 0; p < 2; ++p) {
      __syncthreads();
      if ((wc >> 6) == p) {
#pragma unroll
        for (int bb = 0; bb < 4; ++bb) {
          int clx = (wc & 63) + bb * 16 + frow;
          float bv = C.bias ? C.bias[col0 + p * 64 + clx] : 0.f;
#pragma unroll
          for (int a = 0; a < 4; ++a) {
#pragma unroll
            for (int g = 0; g < 4; ++g) {
              int rlx = wr + a * 16 + lg4 + g;
              unsigned short th, tl;
              split_bf16(acc[a][bb][g] + bv, th, tl);
              Th[clx][rlx] = th; Tl[clx][rlx] = tl;
            }
          }
        }
      }
      __syncthreads();
#pragma unroll
      for (int m = 0; m < 4; ++m) {
        int s = tid + 256 * m;
        int dd = s >> 4, tb = (s & 15) * 8;
        int colg = col0 + p * 64 + dd;
        long gi = (((long)bbat * 8 + (colg >> 6)) * 64 + (colg & 63)) * 1024 + tok0 + tb;
        *(us8v*)&C.ch[gi] = *(const us8v*)&Th[dd][tb];
        *(us8v*)&C.cl[gi] = *(const us8v*)&Tl[dd][tb];
      }
    }
  }
}

// ---------------------------------------------------------------------------
// uk[b,h,t] = u[h]·k[b,t,h,:], vr[h,l] = v[h]·r[l,h,:].
// ---------------------------------------------------------------------------
__global__ __launch_bounds__(256)
void ukvr_kernel(const unsigned short* __restrict__ kh, const unsigned short* __restrict__ kl,
                 const unsigned short* __restrict__ rh, const unsigned short* __restrict__ rl,
                 const float* __restrict__ u, const float* __restrict__ v,
                 float* __restrict__ uk, float* __restrict__ vr) {
  int wg = (blockIdx.x * 256 + threadIdx.x) >> 6;
  int lane = threadIdx.x & 63;
  int hh = lane >> 3;
  int d8 = (lane & 7) * 8;
  bool isuk = wg < 4096;
  const unsigned short* sh; const unsigned short* sl; const float* cf; long row;
  if (isuk) { sh = kh; sl = kl; cf = u; row = wg; }
  else { sh = rh; sl = rl; cf = v; row = min(wg - 4096, L_ - 1); }
  long gi = row * 512 + hh * 64 + d8;
  us8v ah = *(const us8v*)&sh[gi];
  us8v al = *(const us8v*)&sl[gi];
  float part = 0.f;
#pragma unroll
  for (int e = 0; e < 8; ++e)
    part += cf[hh * 64 + d8 + e] * (bf2f(ah[e]) + bf2f(al[e]));
  part += __shfl_xor(part, 1);
  part += __shfl_xor(part, 2);
  part += __shfl_xor(part, 4);
  if ((lane & 7) == 0) {
    if (isuk) uk[(wg >> 10) * 8192 + hh * 1024 + (wg & 1023)] = part;
    else vr[hh * 2048 + (wg - 4096)] = part;
  }
}

// ---------------------------------------------------------------------------
// Fused rel-pos attention, split-bf16 MFMA (unchanged from round 4).
// ---------------------------------------------------------------------------
__global__ __launch_bounds__(512)
void attn_mfma2(const unsigned short* __restrict__ qhp, const unsigned short* __restrict__ qlp,
                const unsigned short* __restrict__ kh, const unsigned short* __restrict__ kl,
                const unsigned short* __restrict__ vth, const unsigned short* __restrict__ vtl,
                const unsigned short* __restrict__ rh, const unsigned short* __restrict__ rl,
                const float* __restrict__ uk, const float* __restrict__ vr,
                unsigned short* __restrict__ oh, unsigned short* __restrict__ ol) {
  const int qt = blockIdx.x, h = blockIdx.y, b = blockIdx.z;
  const int q0 = qt * 128;
  const int tid = threadIdx.x;
  const int lane = tid & 63;
  const int wid = tid >> 6;
  const int lr = lane & 15;
  const int lg = lane >> 4;

  __shared__ unsigned short Kh[64][68], Kl[64][68];
  __shared__ unsigned short Vh[64][68], Vl[64][68];
  __shared__ unsigned short RWh[192][68], RWl[192][68];
  __shared__ unsigned short Ph[128][68], Pl[128][68];

  bf16x8 quh[2], qul[2];
  {
    long qoff = (long)(b * T_ + q0 + wid * 16 + lr) * 512 + h * 64 + lg * 8;
    quh[0] = *(const bf16x8*)&qhp[qoff];
    quh[1] = *(const bf16x8*)&qhp[qoff + 32];
    qul[0] = *(const bf16x8*)&qlp[qoff];
    qul[1] = *(const bf16x8*)&qlp[qoff + 32];
  }

  f32x4 pv[4];
#pragma unroll
  for (int c = 0; c < 4; ++c) pv[c] = (f32x4){0.f, 0.f, 0.f, 0.f};
  float m_run[4], l_run[4];
#pragma unroll
  for (int r = 0; r < 4; ++r) { m_run[r] = -3.0e38f; l_run[r] = 0.f; }

  const int band0 = 112 - wid * 16;
  const int sbase0 = 14 - 2 * qt;
  const float* ukrow = uk + ((long)b * 8 + h) * 1024;
  const float* vrrow = vr + (long)h * 2048;
  const int stj = tid >> 3;
  const int std8 = (tid & 7) * 8;

  for (int t = 0; t < 16; ++t) {
    const int j0 = t * 64;
    __syncthreads();

    { long gi = (long)(b * T_ + j0 + stj) * 512 + h * 64 + std8;
      *(us8v*)&Kh[stj][std8] = *(const us8v*)&kh[gi];
      *(us8v*)&Kl[stj][std8] = *(const us8v*)&kl[gi]; }
    { long gi = (((long)b * 8 + h) * 64 + stj) * 1024 + j0 + std8;
      *(us8v*)&Vh[stj][std8] = *(const us8v*)&vth[gi];
      *(us8v*)&Vl[stj][std8] = *(const us8v*)&vtl[gi]; }
    if (t == 0) {
#pragma unroll
      for (int ss = 0; ss < 2; ++ss) {
        int seg = sbase0 + ss;
        int slot = seg % 3;
        long A = min(seg * 64 + stj, L_ - 1);
        long gi = A * 512 + h * 64 + std8;
        *(us8v*)&RWh[slot * 64 + stj][std8] = *(const us8v*)&rh[gi];
        *(us8v*)&RWl[slot * 64 + stj][std8] = *(const us8v*)&rl[gi];
      }
    }
    { int seg = sbase0 + t + 2;
      int slot = seg % 3;
      long A = min(seg * 64 + stj, L_ - 1);
      long gi = A * 512 + h * 64 + std8;
      *(us8v*)&RWh[slot * 64 + stj][std8] = *(const us8v*)&rh[gi];
      *(us8v*)&RWl[slot * 64 + stj][std8] = *(const us8v*)&rl[gi]; }
    __syncthreads();

    f32x4 ac[4], bda[5];
#pragma unroll
    for (int c = 0; c < 4; ++c) ac[c] = (f32x4){0.f, 0.f, 0.f, 0.f};
#pragma unroll
    for (int c = 0; c < 5; ++c) bda[c] = (f32x4){0.f, 0.f, 0.f, 0.f};

#pragma unroll
    for (int ks = 0; ks < 2; ++ks) {
#pragma unroll
      for (int c = 0; c < 4; ++c) {
        bf16x8 kbh = *(const bf16x8*)&Kh[c * 16 + lr][ks * 32 + lg * 8];
        bf16x8 kbl = *(const bf16x8*)&Kl[c * 16 + lr][ks * 32 + lg * 8];
        ac[c] = __builtin_amdgcn_mfma_f32_16x16x32_bf16(quh[ks], kbh, ac[c], 0, 0, 0);
        ac[c] = __builtin_amdgcn_mfma_f32_16x16x32_bf16(quh[ks], kbl, ac[c], 0, 0, 0);
        ac[c] = __builtin_amdgcn_mfma_f32_16x16x32_bf16(qul[ks], kbh, ac[c], 0, 0, 0);
      }
#pragma unroll
      for (int c = 0; c < 5; ++c) {
        int off = band0 + c * 16;
        int slot = (sbase0 + t + (off >> 6)) % 3;
        int rrow = slot * 64 + (off & 63) + lr;
        bf16x8 rbh = *(const bf16x8*)&RWh[rrow][ks * 32 + lg * 8];
        bf16x8 rbl = *(const bf16x8*)&RWl[rrow][ks * 32 + lg * 8];
        bda[c] = __builtin_amdgcn_mfma_f32_16x16x32_bf16(quh[ks], rbh, bda[c], 0, 0, 0);
        bda[c] = __builtin_amdgcn_mfma_f32_16x16x32_bf16(quh[ks], rbl, bda[c], 0, 0, 0);
        bda[c] = __builtin_amdgcn_mfma_f32_16x16x32_bf16(qul[ks], rbh, bda[c], 0, 0, 0);
      }
    }

    const int wbase = 896 - q0 + j0;
#pragma unroll
    for (int c = 0; c < 5; ++c) {
      float vv = vrrow[wbase + band0 + c * 16 + lr];
#pragma unroll
      for (int r = 0; r < 4; ++r) bda[c][r] += vv;
    }

    float p_[4][4];
#pragma unroll
    for (int r = 0; r < 4; ++r) {
      int rowl = lg * 4 + r;
      int e = lr - rowl + 15;
      int srcl = lg * 16 + (e & 15);
      int carry = e >> 4;
      float s0 = __shfl(bda[0][r], srcl);
      float s1 = __shfl(bda[1][r], srcl);
      float s2 = __shfl(bda[2][r], srcl);
      float s3 = __shfl(bda[3][r], srcl);
      float s4 = __shfl(bda[4][r], srcl);
      p_[0][r] = carry ? s1 : s0;
      p_[1][r] = carry ? s2 : s1;
      p_[2][r] = carry ? s3 : s2;
      p_[3][r] = carry ? s4 : s3;
    }
#pragma unroll
    for (int c = 0; c < 4; ++c) {
      float ukv = ukrow[j0 + c * 16 + lr];
#pragma unroll
      for (int r = 0; r < 4; ++r)
        p_[c][r] = (ac[c][r] + p_[c][r] + ukv) * 0.125f;
    }

#pragma unroll
    for (int r = 0; r < 4; ++r) {
      float lm = fmaxf(fmaxf(p_[0][r], p_[1][r]), fmaxf(p_[2][r], p_[3][r]));
#pragma unroll
      for (int off = 1; off < 16; off <<= 1)
        lm = fmaxf(lm, __shfl_xor(lm, off));
      float mnew = fmaxf(m_run[r], lm);
      float rescale = __expf(m_run[r] - mnew);
      float srow = 0.f;
#pragma unroll
      for (int c = 0; c < 4; ++c) {
        float pe = __expf(p_[c][r] - mnew);
        p_[c][r] = pe;
        srow += pe;
      }
#pragma unroll
      for (int off = 1; off < 16; off <<= 1)
        srow += __shfl_xor(srow, off);
      l_run[r] = l_run[r] * rescale + srow;
      m_run[r] = mnew;
#pragma unroll
      for (int c = 0; c < 4; ++c) pv[c][r] *= rescale;
    }

#pragma unroll
    for (int c = 0; c < 4; ++c)
#pragma unroll
      for (int r = 0; r < 4; ++r) {
        unsigned short th, tl;
        split_bf16(p_[c][r], th, tl);
        Ph[wid * 16 + lg * 4 + r][c * 16 + lr] = th;
        Pl[wid * 16 + lg * 4 + r][c * 16 + lr] = tl;
      }

#pragma unroll
    for (int ks = 0; ks < 2; ++ks) {
      bf16x8 pah = *(const bf16x8*)&Ph[wid * 16 + lr][ks * 32 + lg * 8];
      bf16x8 pal = *(const bf16x8*)&Pl[wid * 16 + lr][ks * 32 + lg * 8];
#pragma unroll
      for (int c = 0; c < 4; ++c) {
        bf16x8 vbh = *(const bf16x8*)&Vh[c * 16 + lr][ks * 32 + lg * 8];
        bf16x8 vbl = *(const bf16x8*)&Vl[c * 16 + lr][ks * 32 + lg * 8];
        pv[c] = __builtin_amdgcn_mfma_f32_16x16x32_bf16(pah, vbh, pv[c], 0, 0, 0);
        pv[c] = __builtin_amdgcn_mfma_f32_16x16x32_bf16(pah, vbl, pv[c], 0, 0, 0);
        pv[c] = __builtin_amdgcn_mfma_f32_16x16x32_bf16(pal, vbh, pv[c], 0, 0, 0);
      }
    }
  }

#pragma unroll
  for (int r = 0; r < 4; ++r) {
    float inv = 1.f / l_run[r];
    long base = (long)(b * T_ + q0 + wid * 16 + lg * 4 + r) * 512 + h * 64;
#pragma unroll
    for (int c = 0; c < 4; ++c) {
      unsigned short th, tl;
      split_bf16(pv[c][r] * inv, th, tl);
      oh[base + c * 16 + lr] = th;
      ol[base + c * 16 + lr] = tl;
    }
  }
}

// ---------------------------------------------------------------------------
extern "C" void kernel_launch(void* const* d_in, const int* in_sizes, int n_in,
                              void* d_out, int out_size, void* d_ws, size_t ws_size,
                              hipStream_t stream) {
  const float* x       = (const float*)d_in[0];
  const float* pos_emb = (const float*)d_in[1];
  const float* Wq      = (const float*)d_in[2];
  const float* bq      = (const float*)d_in[3];
  const float* Wk      = (const float*)d_in[4];
  const float* bk      = (const float*)d_in[5];
  const float* Wv      = (const float*)d_in[6];
  const float* bv      = (const float*)d_in[7];
  const float* Wr      = (const float*)d_in[8];
  const float* Wo      = (const float*)d_in[9];
  const float* bo      = (const float*)d_in[10];
  const float* u       = (const float*)d_in[11];
  const float* v       = (const float*)d_in[12];

  float* out = (float*)d_out;
  unsigned short* us = (unsigned short*)d_ws;
  const long S = 2097152;   // MT * D

  unsigned short* qh  = us;
  unsigned short* ql  = us + S;
  unsigned short* kh  = us + 2 * S;
  unsigned short* kl  = us + 3 * S;
  unsigned short* vth = us + 4 * S;
  unsigned short* vtl = us + 5 * S;
  unsigned short* rh  = us + 6 * S;              // 2048*512
  unsigned short* rl  = rh + 1048576;
  unsigned short* xh  = us + 7 * S;              // -> atth after QKV
  unsigned short* xl  = us + 8 * S;
  unsigned short* ph  = us + 9 * S;              // pos split, 2048*512
  unsigned short* pl  = ph + 1048576;
  unsigned short* wth = us + 10 * S;             // 5 x 262144
  unsigned short* wtl = wth + 1310720;
  float* uk = (float*)(wtl + 1310720);           // [4][8][1024]
  float* vr = uk + 32768;                        // [8][2048]

  conv_flat<<<3072, 256, 0, stream>>>(x, xh, xl, pos_emb, ph, pl);
  conv_wt<<<dim3(8, 8, 5), 256, 0, stream>>>(Wq, Wk, Wv, Wr, Wo, wth, wtl);

  EpCfg cq{wth,            wtl,            bq,      nullptr, qh,  ql,  1};
  EpCfg ck{wth + 262144,   wtl + 262144,   bk,      nullptr, kh,  kl,  1};
  EpCfg cv{wth + 524288,   wtl + 524288,   bv,      nullptr, vth, vtl, 2};
  gemm3<<<dim3(32, 12), 256, 0, stream>>>(xh, xl, cq, ck, cv, 4096);

  EpCfg cr{wth + 786432,   wtl + 786432,   nullptr, nullptr, rh,  rl,  1};
  gemm3<<<dim3(16, 4), 256, 0, stream>>>(ph, pl, cr, cr, cr, 2047);

  ukvr_kernel<<<1536, 256, 0, stream>>>(kh, kl, rh, rl, u, v, uk, vr);

  attn_mfma2<<<dim3(8, 8, 4), 512, 0, stream>>>(qh, ql, kh, kl, vth, vtl, rh, rl,
                                                uk, vr, xh, xl);

  EpCfg co{wth + 1048576,  wtl + 1048576,  bo,      out,     nullptr, nullptr, 0};
  gemm3<<<dim3(32, 4), 256, 0, stream>>>(xh, xl, co, co, co, 4096);
}

// Round 7
// 231.577 us; speedup vs baseline: 1.7879x; 1.6547x over previous
//
#include <hip/hip_runtime.h>

#define B_ 4
#define T_ 1024
#define D_ 512
#define H_ 8
#define DH_ 64
#define L_ 2047

typedef __attribute__((ext_vector_type(8))) short bf16x8;
typedef __attribute__((ext_vector_type(4))) float f32x4;
typedef __attribute__((ext_vector_type(8))) unsigned short us8v;
typedef __attribute__((ext_vector_type(4))) unsigned short us4v;

__device__ __forceinline__ void split_bf16(float a, unsigned short& h, unsigned short& l) {
  unsigned u = __float_as_uint(a);
  h = (unsigned short)(u >> 16);
  float hf = __uint_as_float(u & 0xFFFF0000u);
  l = (unsigned short)(__float_as_uint(a - hf) >> 16);
}
__device__ __forceinline__ float bf2f(unsigned short s) {
  return __uint_as_float(((unsigned)s) << 16);
}
__device__ __forceinline__ void gload16(const unsigned short* g, unsigned short* l) {
  __builtin_amdgcn_global_load_lds(
      (const __attribute__((address_space(1))) void*)g,
      (__attribute__((address_space(3))) void*)l, 16, 0, 0);
}

// ---------------------------------------------------------------------------
// Flat split: x (2048 blocks) + pos_emb (1024 blocks, guarded tail).
// ---------------------------------------------------------------------------
__global__ __launch_bounds__(256)
void conv_flat(const float* __restrict__ x, unsigned short* __restrict__ xh,
               unsigned short* __restrict__ xl,
               const float* __restrict__ p, unsigned short* __restrict__ ph,
               unsigned short* __restrict__ pl) {
  int blk = blockIdx.x;
  const float* in; unsigned short* oh; unsigned short* ol; long n, base;
  if (blk < 2048) { in = x; oh = xh; ol = xl; n = 2097152; base = (long)blk * 1024; }
  else { in = p; oh = ph; ol = pl; n = 1048064; base = (long)(blk - 2048) * 1024; }
  long i = base + threadIdx.x * 4;
  if (i + 4 <= n) {
    float4 a = *(const float4*)&in[i];
    us4v h, l; unsigned short th, tl;
    split_bf16(a.x, th, tl); h[0] = th; l[0] = tl;
    split_bf16(a.y, th, tl); h[1] = th; l[1] = tl;
    split_bf16(a.z, th, tl); h[2] = th; l[2] = tl;
    split_bf16(a.w, th, tl); h[3] = th; l[3] = tl;
    *(us4v*)&oh[i] = h; *(us4v*)&ol[i] = l;
  } else {
    for (long e = i; e < n; ++e) {
      unsigned short th, tl; split_bf16(in[e], th, tl); oh[e] = th; ol[e] = tl;
    }
  }
}

// ---------------------------------------------------------------------------
// Weight split + transpose: W[k][n] fp32 -> Wt_h/Wt_l [n][k] bf16.
// ---------------------------------------------------------------------------
__global__ __launch_bounds__(256)
void conv_wt(const float* w0, const float* w1, const float* w2, const float* w3,
             const float* w4, unsigned short* __restrict__ wth,
             unsigned short* __restrict__ wtl) {
  const float* W = blockIdx.z == 0 ? w0 : blockIdx.z == 1 ? w1 :
                   blockIdx.z == 2 ? w2 : blockIdx.z == 3 ? w3 : w4;
  unsigned short* oh = wth + (long)blockIdx.z * 262144;
  unsigned short* ol = wtl + (long)blockIdx.z * 262144;
  __shared__ unsigned short Th[64][72], Tl[64][72];
  const int k0 = blockIdx.x * 64, n0 = blockIdx.y * 64;
  const int tid = threadIdx.x;
#pragma unroll
  for (int m = 0; m < 4; ++m) {
    int s = tid + 256 * m;
    int kk = s >> 4, n4 = (s & 15) * 4;
    float4 a = *(const float4*)&W[(long)(k0 + kk) * 512 + n0 + n4];
    unsigned short th, tl;
    split_bf16(a.x, th, tl); Th[n4 + 0][kk] = th; Tl[n4 + 0][kk] = tl;
    split_bf16(a.y, th, tl); Th[n4 + 1][kk] = th; Tl[n4 + 1][kk] = tl;
    split_bf16(a.z, th, tl); Th[n4 + 2][kk] = th; Tl[n4 + 2][kk] = tl;
    split_bf16(a.w, th, tl); Th[n4 + 3][kk] = th; Tl[n4 + 3][kk] = tl;
  }
  __syncthreads();
#pragma unroll
  for (int m = 0; m < 2; ++m) {
    int s = tid + 256 * m;
    int nn = s >> 3, kb = (s & 7) * 8;
    *(us8v*)&oh[(long)(n0 + nn) * 512 + k0 + kb] = *(const us8v*)&Th[nn][kb];
    *(us8v*)&ol[(long)(n0 + nn) * 512 + k0 + kb] = *(const us8v*)&Tl[nn][kb];
  }
}

// ---------------------------------------------------------------------------
// Split-bf16 MFMA GEMM v4: async global_load_lds + double-buffered LDS.
// BM=128 BN=64 BK=32, 256 thr / 4 waves (2 row x 2 col), wave tile 64x32.
// LDS linear [rows][32] per array (gload_lds constraint); bank conflicts fixed
// by XOR chunk-swizzle applied to the per-lane global SOURCE address and to
// the frag ds_read (guide rule 21): phys_chunk = logical ^ ((row>>1)&3).
// One __syncthreads per k-step: its vmcnt-drain is the dbuf handshake (m97).
// ---------------------------------------------------------------------------
struct EpCfg {
  const unsigned short* wth;
  const unsigned short* wtl;
  const float* bias;
  float* cf;
  unsigned short* ch;
  unsigned short* cl;
  int ep;
};

__global__ __launch_bounds__(256)
void gemm4(const unsigned short* __restrict__ Ag_h, const unsigned short* __restrict__ Ag_l,
           EpCfg e0, EpCfg e1, EpCfg e2, int mlimit) {
  // buffer layout (shorts): Ah@0 (128x32), Al@4096, Bh@8192 (64x32), Bl@10240
  // buffer stride 12288; double buffer -> 24576 shorts = 48 KB
  __shared__ unsigned short SMEM[24576];

  const int tid = threadIdx.x;
  const int row0 = blockIdx.x * 128;
  const int cg0 = blockIdx.y * 64;
  const int wsel = cg0 >> 9;
  const int col0 = cg0 & 511;
  const EpCfg C = wsel == 0 ? e0 : (wsel == 1 ? e1 : e2);

  const int lane = tid & 63;
  const int w = tid >> 6;
  const int wr = (w >> 1) * 64;
  const int wc = (w & 1) * 32;
  const int frow = lane & 15;
  const int lg = lane >> 4;          // logical k-chunk of this lane's frags
  const int mlim1 = mlimit - 1;

  // staging lane constants
  const int lrow = lane >> 2;                          // row within 16-row chunk
  const int lcs = (((lane & 3) ^ ((lane >> 3) & 3)) << 3);  // swizzled k-offset (shorts)

#define STAGE(base, kt) do {                                                   \
    const int k0s = (kt) * 32;                                                 \
    _Pragma("unroll")                                                          \
    for (int cc = 0; cc < 2; ++cc) {                                           \
      int c = w + 4 * cc;                                                      \
      int gr = min(row0 + (c << 4) + lrow, mlim1);                             \
      long gi = (long)gr * 512 + k0s + lcs;                                    \
      gload16(&Ag_h[gi], &SMEM[(base) + (c << 9)]);                            \
      gload16(&Ag_l[gi], &SMEM[(base) + 4096 + (c << 9)]);                     \
    }                                                                          \
    { int gc = col0 + (w << 4) + lrow;                                         \
      long gi = (long)gc * 512 + k0s + lcs;                                    \
      gload16(&C.wth[gi], &SMEM[(base) + 8192 + (w << 9)]);                    \
      gload16(&C.wtl[gi], &SMEM[(base) + 10240 + (w << 9)]); }                 \
  } while (0)

  f32x4 acc[4][2];
#pragma unroll
  for (int a = 0; a < 4; ++a)
#pragma unroll
    for (int bb = 0; bb < 2; ++bb) acc[a][bb] = (f32x4){0.f, 0.f, 0.f, 0.f};

  STAGE(0, 0);
  __syncthreads();   // drain vmcnt: buf0 ready

  for (int t = 0; t < 16; ++t) {
    const int cur = (t & 1) * 12288;
    if (t < 15) STAGE(12288 - cur, t + 1);   // async into other buffer

    const unsigned short* Abh = &SMEM[cur];
    const unsigned short* Abl = &SMEM[cur + 4096];
    const unsigned short* Bbh = &SMEM[cur + 8192];
    const unsigned short* Bbl = &SMEM[cur + 10240];

    bf16x8 bhf[2], blf[2];
#pragma unroll
    for (int bb = 0; bb < 2; ++bb) {
      int rB = wc + bb * 16 + frow;
      int off = rB * 32 + ((lg ^ ((rB >> 1) & 3)) << 3);
      bhf[bb] = *(const bf16x8*)&Bbh[off];
      blf[bb] = *(const bf16x8*)&Bbl[off];
    }
#pragma unroll
    for (int a = 0; a < 4; ++a) {
      int rA = wr + a * 16 + frow;
      int offA = rA * 32 + ((lg ^ ((rA >> 1) & 3)) << 3);
      bf16x8 ah = *(const bf16x8*)&Abh[offA];
      bf16x8 al = *(const bf16x8*)&Abl[offA];
#pragma unroll
      for (int bb = 0; bb < 2; ++bb) {
        acc[a][bb] = __builtin_amdgcn_mfma_f32_16x16x32_bf16(ah, bhf[bb], acc[a][bb], 0, 0, 0);
        acc[a][bb] = __builtin_amdgcn_mfma_f32_16x16x32_bf16(ah, blf[bb], acc[a][bb], 0, 0, 0);
        acc[a][bb] = __builtin_amdgcn_mfma_f32_16x16x32_bf16(al, bhf[bb], acc[a][bb], 0, 0, 0);
      }
    }
    __syncthreads();  // drains next-buf stage (vmcnt) + protects cur for restage
  }
#undef STAGE

  const int lg4 = (lane >> 4) * 4;

  if (C.ep == 0) {
    // fp32 direct: lanes 0-15 contiguous -> 64B segments
#pragma unroll
    for (int bb = 0; bb < 2; ++bb) {
      int col = col0 + wc + bb * 16 + frow;
      float bv = C.bias ? C.bias[col] : 0.f;
#pragma unroll
      for (int a = 0; a < 4; ++a) {
#pragma unroll
        for (int g = 0; g < 4; ++g) {
          int row = row0 + wr + a * 16 + lg4 + g;
          if (row < mlimit) C.cf[(long)row * 512 + col] = acc[a][bb][g] + bv;
        }
      }
    }
  } else if (C.ep == 1) {
    // split-pair bounced epilogue, two 64-row passes
    unsigned short (*Th)[72] = (unsigned short (*)[72])&SMEM[0];     // 64x72
    unsigned short (*Tl)[72] = (unsigned short (*)[72])&SMEM[4608];
#pragma unroll
    for (int p = 0; p < 2; ++p) {
      __syncthreads();
      if ((wr >> 6) == p) {
#pragma unroll
        for (int bb = 0; bb < 2; ++bb) {
          int clx = wc + bb * 16 + frow;
          float bv = C.bias ? C.bias[col0 + clx] : 0.f;
#pragma unroll
          for (int a = 0; a < 4; ++a) {
#pragma unroll
            for (int g = 0; g < 4; ++g) {
              unsigned short th, tl;
              split_bf16(acc[a][bb][g] + bv, th, tl);
              int rlx = a * 16 + lg4 + g;
              Th[rlx][clx] = th; Tl[rlx][clx] = tl;
            }
          }
        }
      }
      __syncthreads();
#pragma unroll
      for (int m = 0; m < 2; ++m) {
        int s = tid + 256 * m;
        int rr = s >> 3, cb = (s & 7) * 8;
        int row = row0 + p * 64 + rr;
        if (row < mlimit) {
          long gi = (long)row * 512 + col0 + cb;
          *(us8v*)&C.ch[gi] = *(const us8v*)&Th[rr][cb];
          *(us8v*)&C.cl[gi] = *(const us8v*)&Tl[rr][cb];
        }
      }
    }
  } else {
    // Vt epilogue: transpose to [b][h][d][token], single pass (64d x 128tok)
    unsigned short (*Th)[136] = (unsigned short (*)[136])&SMEM[0];     // 64x136
    unsigned short (*Tl)[136] = (unsigned short (*)[136])&SMEM[8704];
    int bbat = row0 >> 10, tok0 = row0 & 1023;
#pragma unroll
    for (int bb = 0; bb < 2; ++bb) {
      int clx = wc + bb * 16 + frow;
      float bv = C.bias ? C.bias[col0 + clx] : 0.f;
#pragma unroll
      for (int a = 0; a < 4; ++a) {
#pragma unroll
        for (int g = 0; g < 4; ++g) {
          int rlx = wr + a * 16 + lg4 + g;
          unsigned short th, tl;
          split_bf16(acc[a][bb][g] + bv, th, tl);
          Th[clx][rlx] = th; Tl[clx][rlx] = tl;
        }
      }
    }
    __syncthreads();
#pragma unroll
    for (int m = 0; m < 4; ++m) {
      int s = tid + 256 * m;
      int dd = s >> 4, tb = (s & 15) * 8;
      int colg = col0 + dd;
      long gi = (((long)bbat * 8 + (colg >> 6)) * 64 + (colg & 63)) * 1024 + tok0 + tb;
      *(us8v*)&C.ch[gi] = *(const us8v*)&Th[dd][tb];
      *(us8v*)&C.cl[gi] = *(const us8v*)&Tl[dd][tb];
    }
  }
}

// ---------------------------------------------------------------------------
// uk[b,h,t] = u[h]·k[b,t,h,:], vr[h,l] = v[h]·r[l,h,:].
// ---------------------------------------------------------------------------
__global__ __launch_bounds__(256)
void ukvr_kernel(const unsigned short* __restrict__ kh, const unsigned short* __restrict__ kl,
                 const unsigned short* __restrict__ rh, const unsigned short* __restrict__ rl,
                 const float* __restrict__ u, const float* __restrict__ v,
                 float* __restrict__ uk, float* __restrict__ vr) {
  int wg = (blockIdx.x * 256 + threadIdx.x) >> 6;
  int lane = threadIdx.x & 63;
  int hh = lane >> 3;
  int d8 = (lane & 7) * 8;
  bool isuk = wg < 4096;
  const unsigned short* sh; const unsigned short* sl; const float* cf; long row;
  if (isuk) { sh = kh; sl = kl; cf = u; row = wg; }
  else { sh = rh; sl = rl; cf = v; row = min(wg - 4096, L_ - 1); }
  long gi = row * 512 + hh * 64 + d8;
  us8v ah = *(const us8v*)&sh[gi];
  us8v al = *(const us8v*)&sl[gi];
  float part = 0.f;
#pragma unroll
  for (int e = 0; e < 8; ++e)
    part += cf[hh * 64 + d8 + e] * (bf2f(ah[e]) + bf2f(al[e]));
  part += __shfl_xor(part, 1);
  part += __shfl_xor(part, 2);
  part += __shfl_xor(part, 4);
  if ((lane & 7) == 0) {
    if (isuk) uk[(wg >> 10) * 8192 + hh * 1024 + (wg & 1023)] = part;
    else vr[hh * 2048 + (wg - 4096)] = part;
  }
}

// ---------------------------------------------------------------------------
// Fused rel-pos attention, split-bf16 MFMA (unchanged from round 4/6).
// ---------------------------------------------------------------------------
__global__ __launch_bounds__(512)
void attn_mfma2(const unsigned short* __restrict__ qhp, const unsigned short* __restrict__ qlp,
                const unsigned short* __restrict__ kh, const unsigned short* __restrict__ kl,
                const unsigned short* __restrict__ vth, const unsigned short* __restrict__ vtl,
                const unsigned short* __restrict__ rh, const unsigned short* __restrict__ rl,
                const float* __restrict__ uk, const float* __restrict__ vr,
                unsigned short* __restrict__ oh, unsigned short* __restrict__ ol) {
  const int qt = blockIdx.x, h = blockIdx.y, b = blockIdx.z;
  const int q0 = qt * 128;
  const int tid = threadIdx.x;
  const int lane = tid & 63;
  const int wid = tid >> 6;
  const int lr = lane & 15;
  const int lg = lane >> 4;

  __shared__ unsigned short Kh[64][68], Kl[64][68];
  __shared__ unsigned short Vh[64][68], Vl[64][68];
  __shared__ unsigned short RWh[192][68], RWl[192][68];
  __shared__ unsigned short Ph[128][68], Pl[128][68];

  bf16x8 quh[2], qul[2];
  {
    long qoff = (long)(b * T_ + q0 + wid * 16 + lr) * 512 + h * 64 + lg * 8;
    quh[0] = *(const bf16x8*)&qhp[qoff];
    quh[1] = *(const bf16x8*)&qhp[qoff + 32];
    qul[0] = *(const bf16x8*)&qlp[qoff];
    qul[1] = *(const bf16x8*)&qlp[qoff + 32];
  }

  f32x4 pv[4];
#pragma unroll
  for (int c = 0; c < 4; ++c) pv[c] = (f32x4){0.f, 0.f, 0.f, 0.f};
  float m_run[4], l_run[4];
#pragma unroll
  for (int r = 0; r < 4; ++r) { m_run[r] = -3.0e38f; l_run[r] = 0.f; }

  const int band0 = 112 - wid * 16;
  const int sbase0 = 14 - 2 * qt;
  const float* ukrow = uk + ((long)b * 8 + h) * 1024;
  const float* vrrow = vr + (long)h * 2048;
  const int stj = tid >> 3;
  const int std8 = (tid & 7) * 8;

  for (int t = 0; t < 16; ++t) {
    const int j0 = t * 64;
    __syncthreads();

    { long gi = (long)(b * T_ + j0 + stj) * 512 + h * 64 + std8;
      *(us8v*)&Kh[stj][std8] = *(const us8v*)&kh[gi];
      *(us8v*)&Kl[stj][std8] = *(const us8v*)&kl[gi]; }
    { long gi = (((long)b * 8 + h) * 64 + stj) * 1024 + j0 + std8;
      *(us8v*)&Vh[stj][std8] = *(const us8v*)&vth[gi];
      *(us8v*)&Vl[stj][std8] = *(const us8v*)&vtl[gi]; }
    if (t == 0) {
#pragma unroll
      for (int ss = 0; ss < 2; ++ss) {
        int seg = sbase0 + ss;
        int slot = seg % 3;
        long A = min(seg * 64 + stj, L_ - 1);
        long gi = A * 512 + h * 64 + std8;
        *(us8v*)&RWh[slot * 64 + stj][std8] = *(const us8v*)&rh[gi];
        *(us8v*)&RWl[slot * 64 + stj][std8] = *(const us8v*)&rl[gi];
      }
    }
    { int seg = sbase0 + t + 2;
      int slot = seg % 3;
      long A = min(seg * 64 + stj, L_ - 1);
      long gi = A * 512 + h * 64 + std8;
      *(us8v*)&RWh[slot * 64 + stj][std8] = *(const us8v*)&rh[gi];
      *(us8v*)&RWl[slot * 64 + stj][std8] = *(const us8v*)&rl[gi]; }
    __syncthreads();

    f32x4 ac[4], bda[5];
#pragma unroll
    for (int c = 0; c < 4; ++c) ac[c] = (f32x4){0.f, 0.f, 0.f, 0.f};
#pragma unroll
    for (int c = 0; c < 5; ++c) bda[c] = (f32x4){0.f, 0.f, 0.f, 0.f};

#pragma unroll
    for (int ks = 0; ks < 2; ++ks) {
#pragma unroll
      for (int c = 0; c < 4; ++c) {
        bf16x8 kbh = *(const bf16x8*)&Kh[c * 16 + lr][ks * 32 + lg * 8];
        bf16x8 kbl = *(const bf16x8*)&Kl[c * 16 + lr][ks * 32 + lg * 8];
        ac[c] = __builtin_amdgcn_mfma_f32_16x16x32_bf16(quh[ks], kbh, ac[c], 0, 0, 0);
        ac[c] = __builtin_amdgcn_mfma_f32_16x16x32_bf16(quh[ks], kbl, ac[c], 0, 0, 0);
        ac[c] = __builtin_amdgcn_mfma_f32_16x16x32_bf16(qul[ks], kbh, ac[c], 0, 0, 0);
      }
#pragma unroll
      for (int c = 0; c < 5; ++c) {
        int off = band0 + c * 16;
        int slot = (sbase0 + t + (off >> 6)) % 3;
        int rrow = slot * 64 + (off & 63) + lr;
        bf16x8 rbh = *(const bf16x8*)&RWh[rrow][ks * 32 + lg * 8];
        bf16x8 rbl = *(const bf16x8*)&RWl[rrow][ks * 32 + lg * 8];
        bda[c] = __builtin_amdgcn_mfma_f32_16x16x32_bf16(quh[ks], rbh, bda[c], 0, 0, 0);
        bda[c] = __builtin_amdgcn_mfma_f32_16x16x32_bf16(quh[ks], rbl, bda[c], 0, 0, 0);
        bda[c] = __builtin_amdgcn_mfma_f32_16x16x32_bf16(qul[ks], rbh, bda[c], 0, 0, 0);
      }
    }

    const int wbase = 896 - q0 + j0;
#pragma unroll
    for (int c = 0; c < 5; ++c) {
      float vv = vrrow[wbase + band0 + c * 16 + lr];
#pragma unroll
      for (int r = 0; r < 4; ++r) bda[c][r] += vv;
    }

    float p_[4][4];
#pragma unroll
    for (int r = 0; r < 4; ++r) {
      int rowl = lg * 4 + r;
      int e = lr - rowl + 15;
      int srcl = lg * 16 + (e & 15);
      int carry = e >> 4;
      float s0 = __shfl(bda[0][r], srcl);
      float s1 = __shfl(bda[1][r], srcl);
      float s2 = __shfl(bda[2][r], srcl);
      float s3 = __shfl(bda[3][r], srcl);
      float s4 = __shfl(bda[4][r], srcl);
      p_[0][r] = carry ? s1 : s0;
      p_[1][r] = carry ? s2 : s1;
      p_[2][r] = carry ? s3 : s2;
      p_[3][r] = carry ? s4 : s3;
    }
#pragma unroll
    for (int c = 0; c < 4; ++c) {
      float ukv = ukrow[j0 + c * 16 + lr];
#pragma unroll
      for (int r = 0; r < 4; ++r)
        p_[c][r] = (ac[c][r] + p_[c][r] + ukv) * 0.125f;
    }

#pragma unroll
    for (int r = 0; r < 4; ++r) {
      float lm = fmaxf(fmaxf(p_[0][r], p_[1][r]), fmaxf(p_[2][r], p_[3][r]));
#pragma unroll
      for (int off = 1; off < 16; off <<= 1)
        lm = fmaxf(lm, __shfl_xor(lm, off));
      float mnew = fmaxf(m_run[r], lm);
      float rescale = __expf(m_run[r] - mnew);
      float srow = 0.f;
#pragma unroll
      for (int c = 0; c < 4; ++c) {
        float pe = __expf(p_[c][r] - mnew);
        p_[c][r] = pe;
        srow += pe;
      }
#pragma unroll
      for (int off = 1; off < 16; off <<= 1)
        srow += __shfl_xor(srow, off);
      l_run[r] = l_run[r] * rescale + srow;
      m_run[r] = mnew;
#pragma unroll
      for (int c = 0; c < 4; ++c) pv[c][r] *= rescale;
    }

#pragma unroll
    for (int c = 0; c < 4; ++c)
#pragma unroll
      for (int r = 0; r < 4; ++r) {
        unsigned short th, tl;
        split_bf16(p_[c][r], th, tl);
        Ph[wid * 16 + lg * 4 + r][c * 16 + lr] = th;
        Pl[wid * 16 + lg * 4 + r][c * 16 + lr] = tl;
      }

#pragma unroll
    for (int ks = 0; ks < 2; ++ks) {
      bf16x8 pah = *(const bf16x8*)&Ph[wid * 16 + lr][ks * 32 + lg * 8];
      bf16x8 pal = *(const bf16x8*)&Pl[wid * 16 + lr][ks * 32 + lg * 8];
#pragma unroll
      for (int c = 0; c < 4; ++c) {
        bf16x8 vbh = *(const bf16x8*)&Vh[c * 16 + lr][ks * 32 + lg * 8];
        bf16x8 vbl = *(const bf16x8*)&Vl[c * 16 + lr][ks * 32 + lg * 8];
        pv[c] = __builtin_amdgcn_mfma_f32_16x16x32_bf16(pah, vbh, pv[c], 0, 0, 0);
        pv[c] = __builtin_amdgcn_mfma_f32_16x16x32_bf16(pah, vbl, pv[c], 0, 0, 0);
        pv[c] = __builtin_amdgcn_mfma_f32_16x16x32_bf16(pal, vbh, pv[c], 0, 0, 0);
      }
    }
  }

#pragma unroll
  for (int r = 0; r < 4; ++r) {
    float inv = 1.f / l_run[r];
    long base = (long)(b * T_ + q0 + wid * 16 + lg * 4 + r) * 512 + h * 64;
#pragma unroll
    for (int c = 0; c < 4; ++c) {
      unsigned short th, tl;
      split_bf16(pv[c][r] * inv, th, tl);
      oh[base + c * 16 + lr] = th;
      ol[base + c * 16 + lr] = tl;
    }
  }
}

// ---------------------------------------------------------------------------
extern "C" void kernel_launch(void* const* d_in, const int* in_sizes, int n_in,
                              void* d_out, int out_size, void* d_ws, size_t ws_size,
                              hipStream_t stream) {
  const float* x       = (const float*)d_in[0];
  const float* pos_emb = (const float*)d_in[1];
  const float* Wq      = (const float*)d_in[2];
  const float* bq      = (const float*)d_in[3];
  const float* Wk      = (const float*)d_in[4];
  const float* bk      = (const float*)d_in[5];
  const float* Wv      = (const float*)d_in[6];
  const float* bv      = (const float*)d_in[7];
  const float* Wr      = (const float*)d_in[8];
  const float* Wo      = (const float*)d_in[9];
  const float* bo      = (const float*)d_in[10];
  const float* u       = (const float*)d_in[11];
  const float* v       = (const float*)d_in[12];

  float* out = (float*)d_out;
  unsigned short* us = (unsigned short*)d_ws;
  const long S = 2097152;   // MT * D

  unsigned short* qh  = us;
  unsigned short* ql  = us + S;
  unsigned short* kh  = us + 2 * S;
  unsigned short* kl  = us + 3 * S;
  unsigned short* vth = us + 4 * S;
  unsigned short* vtl = us + 5 * S;
  unsigned short* rh  = us + 6 * S;              // 2048*512
  unsigned short* rl  = rh + 1048576;
  unsigned short* xh  = us + 7 * S;              // -> atth after QKV
  unsigned short* xl  = us + 8 * S;
  unsigned short* ph  = us + 9 * S;              // pos split, 2048*512
  unsigned short* pl  = ph + 1048576;
  unsigned short* wth = us + 10 * S;             // 5 x 262144
  unsigned short* wtl = wth + 1310720;
  float* uk = (float*)(wtl + 1310720);           // [4][8][1024]
  float* vr = uk + 32768;                        // [8][2048]

  conv_flat<<<3072, 256, 0, stream>>>(x, xh, xl, pos_emb, ph, pl);
  conv_wt<<<dim3(8, 8, 5), 256, 0, stream>>>(Wq, Wk, Wv, Wr, Wo, wth, wtl);

  EpCfg cq{wth,            wtl,            bq,      nullptr, qh,  ql,  1};
  EpCfg ck{wth + 262144,   wtl + 262144,   bk,      nullptr, kh,  kl,  1};
  EpCfg cv{wth + 524288,   wtl + 524288,   bv,      nullptr, vth, vtl, 2};
  gemm4<<<dim3(32, 24), 256, 0, stream>>>(xh, xl, cq, ck, cv, 4096);

  EpCfg cr{wth + 786432,   wtl + 786432,   nullptr, nullptr, rh,  rl,  1};
  gemm4<<<dim3(16, 8), 256, 0, stream>>>(ph, pl, cr, cr, cr, 2047);

  ukvr_kernel<<<1536, 256, 0, stream>>>(kh, kl, rh, rl, u, v, uk, vr);

  attn_mfma2<<<dim3(8, 8, 4), 512, 0, stream>>>(qh, ql, kh, kl, vth, vtl, rh, rl,
                                                uk, vr, xh, xl);

  EpCfg co{wth + 1048576,  wtl + 1048576,  bo,      out,     nullptr, nullptr, 0};
  gemm4<<<dim3(32, 8), 256, 0, stream>>>(xh, xl, co, co, co, 4096);
}

// Round 9
// 229.257 us; speedup vs baseline: 1.8060x; 1.0101x over previous
//
#include <hip/hip_runtime.h>

#define B_ 4
#define T_ 1024
#define D_ 512
#define H_ 8
#define DH_ 64
#define L_ 2047

typedef __attribute__((ext_vector_type(8))) short bf16x8;
typedef __attribute__((ext_vector_type(4))) float f32x4;
typedef __attribute__((ext_vector_type(8))) unsigned short us8v;
typedef __attribute__((ext_vector_type(4))) unsigned short us4v;

__device__ __forceinline__ void split_bf16(float a, unsigned short& h, unsigned short& l) {
  unsigned u = __float_as_uint(a);
  h = (unsigned short)(u >> 16);
  float hf = __uint_as_float(u & 0xFFFF0000u);
  l = (unsigned short)(__float_as_uint(a - hf) >> 16);
}
__device__ __forceinline__ float bf2f(unsigned short s) {
  return __uint_as_float(((unsigned)s) << 16);
}
__device__ __forceinline__ void gload16(const unsigned short* g, unsigned short* l) {
  __builtin_amdgcn_global_load_lds(
      (const __attribute__((address_space(1))) void*)g,
      (__attribute__((address_space(3))) void*)l, 16, 0, 0);
}

// ---------------------------------------------------------------------------
// Flat split: x (2048 blocks) + pos_emb (1024 blocks, guarded tail).
// ---------------------------------------------------------------------------
__global__ __launch_bounds__(256)
void conv_flat(const float* __restrict__ x, unsigned short* __restrict__ xh,
               unsigned short* __restrict__ xl,
               const float* __restrict__ p, unsigned short* __restrict__ ph,
               unsigned short* __restrict__ pl) {
  int blk = blockIdx.x;
  const float* in; unsigned short* oh; unsigned short* ol; long n, base;
  if (blk < 2048) { in = x; oh = xh; ol = xl; n = 2097152; base = (long)blk * 1024; }
  else { in = p; oh = ph; ol = pl; n = 1048064; base = (long)(blk - 2048) * 1024; }
  long i = base + threadIdx.x * 4;
  if (i + 4 <= n) {
    float4 a = *(const float4*)&in[i];
    us4v h, l; unsigned short th, tl;
    split_bf16(a.x, th, tl); h[0] = th; l[0] = tl;
    split_bf16(a.y, th, tl); h[1] = th; l[1] = tl;
    split_bf16(a.z, th, tl); h[2] = th; l[2] = tl;
    split_bf16(a.w, th, tl); h[3] = th; l[3] = tl;
    *(us4v*)&oh[i] = h; *(us4v*)&ol[i] = l;
  } else {
    for (long e = i; e < n; ++e) {
      unsigned short th, tl; split_bf16(in[e], th, tl); oh[e] = th; ol[e] = tl;
    }
  }
}

// ---------------------------------------------------------------------------
// Weight split + transpose: W[k][n] fp32 -> Wt_h/Wt_l [n][k] bf16.
// ---------------------------------------------------------------------------
__global__ __launch_bounds__(256)
void conv_wt(const float* w0, const float* w1, const float* w2, const float* w3,
             const float* w4, unsigned short* __restrict__ wth,
             unsigned short* __restrict__ wtl) {
  const float* W = blockIdx.z == 0 ? w0 : blockIdx.z == 1 ? w1 :
                   blockIdx.z == 2 ? w2 : blockIdx.z == 3 ? w3 : w4;
  unsigned short* oh = wth + (long)blockIdx.z * 262144;
  unsigned short* ol = wtl + (long)blockIdx.z * 262144;
  __shared__ unsigned short Th[64][72], Tl[64][72];
  const int k0 = blockIdx.x * 64, n0 = blockIdx.y * 64;
  const int tid = threadIdx.x;
#pragma unroll
  for (int m = 0; m < 4; ++m) {
    int s = tid + 256 * m;
    int kk = s >> 4, n4 = (s & 15) * 4;
    float4 a = *(const float4*)&W[(long)(k0 + kk) * 512 + n0 + n4];
    unsigned short th, tl;
    split_bf16(a.x, th, tl); Th[n4 + 0][kk] = th; Tl[n4 + 0][kk] = tl;
    split_bf16(a.y, th, tl); Th[n4 + 1][kk] = th; Tl[n4 + 1][kk] = tl;
    split_bf16(a.z, th, tl); Th[n4 + 2][kk] = th; Tl[n4 + 2][kk] = tl;
    split_bf16(a.w, th, tl); Th[n4 + 3][kk] = th; Tl[n4 + 3][kk] = tl;
  }
  __syncthreads();
#pragma unroll
  for (int m = 0; m < 2; ++m) {
    int s = tid + 256 * m;
    int nn = s >> 3, kb = (s & 7) * 8;
    *(us8v*)&oh[(long)(n0 + nn) * 512 + k0 + kb] = *(const us8v*)&Th[nn][kb];
    *(us8v*)&ol[(long)(n0 + nn) * 512 + k0 + kb] = *(const us8v*)&Tl[nn][kb];
  }
}

// ---------------------------------------------------------------------------
// Split-bf16 MFMA GEMM v4 (unchanged from round 7): async global_load_lds +
// double-buffered LDS, BM=128 BN=64 BK=32, source-side XOR swizzle.
// ---------------------------------------------------------------------------
struct EpCfg {
  const unsigned short* wth;
  const unsigned short* wtl;
  const float* bias;
  float* cf;
  unsigned short* ch;
  unsigned short* cl;
  int ep;
};

__global__ __launch_bounds__(256)
void gemm4(const unsigned short* __restrict__ Ag_h, const unsigned short* __restrict__ Ag_l,
           EpCfg e0, EpCfg e1, EpCfg e2, int mlimit) {
  __shared__ unsigned short SMEM[24576];

  const int tid = threadIdx.x;
  const int row0 = blockIdx.x * 128;
  const int cg0 = blockIdx.y * 64;
  const int wsel = cg0 >> 9;
  const int col0 = cg0 & 511;
  const EpCfg C = wsel == 0 ? e0 : (wsel == 1 ? e1 : e2);

  const int lane = tid & 63;
  const int w = tid >> 6;
  const int wr = (w >> 1) * 64;
  const int wc = (w & 1) * 32;
  const int frow = lane & 15;
  const int lg = lane >> 4;
  const int mlim1 = mlimit - 1;

  const int lrow = lane >> 2;
  const int lcs = (((lane & 3) ^ ((lane >> 3) & 3)) << 3);

#define STAGE(base, kt) do {                                                   \
    const int k0s = (kt) * 32;                                                 \
    _Pragma("unroll")                                                          \
    for (int cc = 0; cc < 2; ++cc) {                                           \
      int c = w + 4 * cc;                                                      \
      int gr = min(row0 + (c << 4) + lrow, mlim1);                             \
      long gi = (long)gr * 512 + k0s + lcs;                                    \
      gload16(&Ag_h[gi], &SMEM[(base) + (c << 9)]);                            \
      gload16(&Ag_l[gi], &SMEM[(base) + 4096 + (c << 9)]);                     \
    }                                                                          \
    { int gc = col0 + (w << 4) + lrow;                                         \
      long gi = (long)gc * 512 + k0s + lcs;                                    \
      gload16(&C.wth[gi], &SMEM[(base) + 8192 + (w << 9)]);                    \
      gload16(&C.wtl[gi], &SMEM[(base) + 10240 + (w << 9)]); }                 \
  } while (0)

  f32x4 acc[4][2];
#pragma unroll
  for (int a = 0; a < 4; ++a)
#pragma unroll
    for (int bb = 0; bb < 2; ++bb) acc[a][bb] = (f32x4){0.f, 0.f, 0.f, 0.f};

  STAGE(0, 0);
  __syncthreads();

  for (int t = 0; t < 16; ++t) {
    const int cur = (t & 1) * 12288;
    if (t < 15) STAGE(12288 - cur, t + 1);

    const unsigned short* Abh = &SMEM[cur];
    const unsigned short* Abl = &SMEM[cur + 4096];
    const unsigned short* Bbh = &SMEM[cur + 8192];
    const unsigned short* Bbl = &SMEM[cur + 10240];

    bf16x8 bhf[2], blf[2];
#pragma unroll
    for (int bb = 0; bb < 2; ++bb) {
      int rB = wc + bb * 16 + frow;
      int off = rB * 32 + ((lg ^ ((rB >> 1) & 3)) << 3);
      bhf[bb] = *(const bf16x8*)&Bbh[off];
      blf[bb] = *(const bf16x8*)&Bbl[off];
    }
#pragma unroll
    for (int a = 0; a < 4; ++a) {
      int rA = wr + a * 16 + frow;
      int offA = rA * 32 + ((lg ^ ((rA >> 1) & 3)) << 3);
      bf16x8 ah = *(const bf16x8*)&Abh[offA];
      bf16x8 al = *(const bf16x8*)&Abl[offA];
#pragma unroll
      for (int bb = 0; bb < 2; ++bb) {
        acc[a][bb] = __builtin_amdgcn_mfma_f32_16x16x32_bf16(ah, bhf[bb], acc[a][bb], 0, 0, 0);
        acc[a][bb] = __builtin_amdgcn_mfma_f32_16x16x32_bf16(ah, blf[bb], acc[a][bb], 0, 0, 0);
        acc[a][bb] = __builtin_amdgcn_mfma_f32_16x16x32_bf16(al, bhf[bb], acc[a][bb], 0, 0, 0);
      }
    }
    __syncthreads();
  }
#undef STAGE

  const int lg4 = (lane >> 4) * 4;

  if (C.ep == 0) {
#pragma unroll
    for (int bb = 0; bb < 2; ++bb) {
      int col = col0 + wc + bb * 16 + frow;
      float bv = C.bias ? C.bias[col] : 0.f;
#pragma unroll
      for (int a = 0; a < 4; ++a) {
#pragma unroll
        for (int g = 0; g < 4; ++g) {
          int row = row0 + wr + a * 16 + lg4 + g;
          if (row < mlimit) C.cf[(long)row * 512 + col] = acc[a][bb][g] + bv;
        }
      }
    }
  } else if (C.ep == 1) {
    unsigned short (*Th)[72] = (unsigned short (*)[72])&SMEM[0];
    unsigned short (*Tl)[72] = (unsigned short (*)[72])&SMEM[4608];
#pragma unroll
    for (int p = 0; p < 2; ++p) {
      __syncthreads();
      if ((wr >> 6) == p) {
#pragma unroll
        for (int bb = 0; bb < 2; ++bb) {
          int clx = wc + bb * 16 + frow;
          float bv = C.bias ? C.bias[col0 + clx] : 0.f;
#pragma unroll
          for (int a = 0; a < 4; ++a) {
#pragma unroll
            for (int g = 0; g < 4; ++g) {
              unsigned short th, tl;
              split_bf16(acc[a][bb][g] + bv, th, tl);
              int rlx = a * 16 + lg4 + g;
              Th[rlx][clx] = th; Tl[rlx][clx] = tl;
            }
          }
        }
      }
      __syncthreads();
#pragma unroll
      for (int m = 0; m < 2; ++m) {
        int s = tid + 256 * m;
        int rr = s >> 3, cb = (s & 7) * 8;
        int row = row0 + p * 64 + rr;
        if (row < mlimit) {
          long gi = (long)row * 512 + col0 + cb;
          *(us8v*)&C.ch[gi] = *(const us8v*)&Th[rr][cb];
          *(us8v*)&C.cl[gi] = *(const us8v*)&Tl[rr][cb];
        }
      }
    }
  } else {
    unsigned short (*Th)[136] = (unsigned short (*)[136])&SMEM[0];
    unsigned short (*Tl)[136] = (unsigned short (*)[136])&SMEM[8704];
    int bbat = row0 >> 10, tok0 = row0 & 1023;
#pragma unroll
    for (int bb = 0; bb < 2; ++bb) {
      int clx = wc + bb * 16 + frow;
      float bv = C.bias ? C.bias[col0 + clx] : 0.f;
#pragma unroll
      for (int a = 0; a < 4; ++a) {
#pragma unroll
        for (int g = 0; g < 4; ++g) {
          int rlx = wr + a * 16 + lg4 + g;
          unsigned short th, tl;
          split_bf16(acc[a][bb][g] + bv, th, tl);
          Th[clx][rlx] = th; Tl[clx][rlx] = tl;
        }
      }
    }
    __syncthreads();
#pragma unroll
    for (int m = 0; m < 4; ++m) {
      int s = tid + 256 * m;
      int dd = s >> 4, tb = (s & 15) * 8;
      int colg = col0 + dd;
      long gi = (((long)bbat * 8 + (colg >> 6)) * 64 + (colg & 63)) * 1024 + tok0 + tb;
      *(us8v*)&C.ch[gi] = *(const us8v*)&Th[dd][tb];
      *(us8v*)&C.cl[gi] = *(const us8v*)&Tl[dd][tb];
    }
  }
}

// ---------------------------------------------------------------------------
// uk[b,h,t] = u[h]·k[b,t,h,:], vr[h,l] = v[h]·r[l,h,:].
// ---------------------------------------------------------------------------
__global__ __launch_bounds__(256)
void ukvr_kernel(const unsigned short* __restrict__ kh, const unsigned short* __restrict__ kl,
                 const unsigned short* __restrict__ rh, const unsigned short* __restrict__ rl,
                 const float* __restrict__ u, const float* __restrict__ v,
                 float* __restrict__ uk, float* __restrict__ vr) {
  int wg = (blockIdx.x * 256 + threadIdx.x) >> 6;
  int lane = threadIdx.x & 63;
  int hh = lane >> 3;
  int d8 = (lane & 7) * 8;
  bool isuk = wg < 4096;
  const unsigned short* sh; const unsigned short* sl; const float* cf; long row;
  if (isuk) { sh = kh; sl = kl; cf = u; row = wg; }
  else { sh = rh; sl = rl; cf = v; row = min(wg - 4096, L_ - 1); }
  long gi = row * 512 + hh * 64 + d8;
  us8v ah = *(const us8v*)&sh[gi];
  us8v al = *(const us8v*)&sl[gi];
  float part = 0.f;
#pragma unroll
  for (int e = 0; e < 8; ++e)
    part += cf[hh * 64 + d8 + e] * (bf2f(ah[e]) + bf2f(al[e]));
  part += __shfl_xor(part, 1);
  part += __shfl_xor(part, 2);
  part += __shfl_xor(part, 4);
  if ((lane & 7) == 0) {
    if (isuk) uk[(wg >> 10) * 8192 + hh * 1024 + (wg & 1023)] = part;
    else vr[hh * 2048 + (wg - 4096)] = part;
  }
}

// ---------------------------------------------------------------------------
// Fused rel-pos attention, split-bf16 MFMA v3:
//  + T14 async-STAGE split (global->reg prefetch issued one iter ahead,
//    ds_write just before use) -- HBM latency hides under compute.
//  + T5 s_setprio(1) around MFMA clusters.
// writeKV(t) stages K/V(t) + RW ring seg sbase0+t+2 (slot (sbase0+t+2)%3).
// Prologue direct-stages t=0 K/V + ring segs sbase0..sbase0+2.
// ---------------------------------------------------------------------------
__global__ __launch_bounds__(512)
void attn_mfma2(const unsigned short* __restrict__ qhp, const unsigned short* __restrict__ qlp,
                const unsigned short* __restrict__ kh, const unsigned short* __restrict__ kl,
                const unsigned short* __restrict__ vth, const unsigned short* __restrict__ vtl,
                const unsigned short* __restrict__ rh, const unsigned short* __restrict__ rl,
                const float* __restrict__ uk, const float* __restrict__ vr,
                unsigned short* __restrict__ oh, unsigned short* __restrict__ ol) {
  const int qt = blockIdx.x, h = blockIdx.y, b = blockIdx.z;
  const int q0 = qt * 128;
  const int tid = threadIdx.x;
  const int lane = tid & 63;
  const int wid = tid >> 6;
  const int lr = lane & 15;
  const int lg = lane >> 4;

  __shared__ unsigned short Kh[64][68], Kl[64][68];
  __shared__ unsigned short Vh[64][68], Vl[64][68];
  __shared__ unsigned short RWh[192][68], RWl[192][68];
  __shared__ unsigned short Ph[128][68], Pl[128][68];

  bf16x8 quh[2], qul[2];
  {
    long qoff = (long)(b * T_ + q0 + wid * 16 + lr) * 512 + h * 64 + lg * 8;
    quh[0] = *(const bf16x8*)&qhp[qoff];
    quh[1] = *(const bf16x8*)&qhp[qoff + 32];
    qul[0] = *(const bf16x8*)&qlp[qoff];
    qul[1] = *(const bf16x8*)&qlp[qoff + 32];
  }

  f32x4 pv[4];
#pragma unroll
  for (int c = 0; c < 4; ++c) pv[c] = (f32x4){0.f, 0.f, 0.f, 0.f};
  float m_run[4], l_run[4];
#pragma unroll
  for (int r = 0; r < 4; ++r) { m_run[r] = -3.0e38f; l_run[r] = 0.f; }

  const int band0 = 112 - wid * 16;
  const int sbase0 = 14 - 2 * qt;
  const float* ukrow = uk + ((long)b * 8 + h) * 1024;
  const float* vrrow = vr + (long)h * 2048;
  const int stj = tid >> 3;
  const int std8 = (tid & 7) * 8;

  // ---- prologue: direct-stage K/V(0) + ring segs sbase0..sbase0+2
  { long gi = (long)(b * T_ + stj) * 512 + h * 64 + std8;
    *(us8v*)&Kh[stj][std8] = *(const us8v*)&kh[gi];
    *(us8v*)&Kl[stj][std8] = *(const us8v*)&kl[gi]; }
  { long gi = (((long)b * 8 + h) * 64 + stj) * 1024 + std8;
    *(us8v*)&Vh[stj][std8] = *(const us8v*)&vth[gi];
    *(us8v*)&Vl[stj][std8] = *(const us8v*)&vtl[gi]; }
#pragma unroll
  for (int ss = 0; ss < 3; ++ss) {
    int seg = sbase0 + ss;
    int slot = seg % 3;
    long A = min(seg * 64 + stj, L_ - 1);
    long gi = A * 512 + h * 64 + std8;
    *(us8v*)&RWh[slot * 64 + stj][std8] = *(const us8v*)&rh[gi];
    *(us8v*)&RWl[slot * 64 + stj][std8] = *(const us8v*)&rl[gi];
  }
  __syncthreads();

  // prefetch registers for stage t+1
  us8v rKh, rKl, rVh, rVl, rRh, rRl;
#define LOADKV(tt) do {                                                        \
    long giK = (long)(b * T_ + (tt) * 64 + stj) * 512 + h * 64 + std8;         \
    rKh = *(const us8v*)&kh[giK];                                              \
    rKl = *(const us8v*)&kl[giK];                                              \
    long giV = (((long)b * 8 + h) * 64 + stj) * 1024 + (tt) * 64 + std8;       \
    rVh = *(const us8v*)&vth[giV];                                             \
    rVl = *(const us8v*)&vtl[giV];                                             \
    int seg_ = sbase0 + (tt) + 2;                                              \
    long A_ = min(seg_ * 64 + stj, L_ - 1);                                    \
    long giR = A_ * 512 + h * 64 + std8;                                       \
    rRh = *(const us8v*)&rh[giR];                                              \
    rRl = *(const us8v*)&rl[giR];                                              \
  } while (0)

  LOADKV(1);

  for (int t = 0; t < 16; ++t) {
    const int j0 = t * 64;

    // ---- AC + BD' MFMAs
    f32x4 ac[4], bda[5];
#pragma unroll
    for (int c = 0; c < 4; ++c) ac[c] = (f32x4){0.f, 0.f, 0.f, 0.f};
#pragma unroll
    for (int c = 0; c < 5; ++c) bda[c] = (f32x4){0.f, 0.f, 0.f, 0.f};

    __builtin_amdgcn_s_setprio(1);
#pragma unroll
    for (int ks = 0; ks < 2; ++ks) {
#pragma unroll
      for (int c = 0; c < 4; ++c) {
        bf16x8 kbh = *(const bf16x8*)&Kh[c * 16 + lr][ks * 32 + lg * 8];
        bf16x8 kbl = *(const bf16x8*)&Kl[c * 16 + lr][ks * 32 + lg * 8];
        ac[c] = __builtin_amdgcn_mfma_f32_16x16x32_bf16(quh[ks], kbh, ac[c], 0, 0, 0);
        ac[c] = __builtin_amdgcn_mfma_f32_16x16x32_bf16(quh[ks], kbl, ac[c], 0, 0, 0);
        ac[c] = __builtin_amdgcn_mfma_f32_16x16x32_bf16(qul[ks], kbh, ac[c], 0, 0, 0);
      }
#pragma unroll
      for (int c = 0; c < 5; ++c) {
        int off = band0 + c * 16;
        int slot = (sbase0 + t + (off >> 6)) % 3;
        int rrow = slot * 64 + (off & 63) + lr;
        bf16x8 rbh = *(const bf16x8*)&RWh[rrow][ks * 32 + lg * 8];
        bf16x8 rbl = *(const bf16x8*)&RWl[rrow][ks * 32 + lg * 8];
        bda[c] = __builtin_amdgcn_mfma_f32_16x16x32_bf16(quh[ks], rbh, bda[c], 0, 0, 0);
        bda[c] = __builtin_amdgcn_mfma_f32_16x16x32_bf16(quh[ks], rbl, bda[c], 0, 0, 0);
        bda[c] = __builtin_amdgcn_mfma_f32_16x16x32_bf16(qul[ks], rbh, bda[c], 0, 0, 0);
      }
    }
    __builtin_amdgcn_s_setprio(0);

    const int wbase = 896 - q0 + j0;
#pragma unroll
    for (int c = 0; c < 5; ++c) {
      float vv = vrrow[wbase + band0 + c * 16 + lr];
#pragma unroll
      for (int r = 0; r < 4; ++r) bda[c][r] += vv;
    }

    float p_[4][4];
#pragma unroll
    for (int r = 0; r < 4; ++r) {
      int rowl = lg * 4 + r;
      int e = lr - rowl + 15;
      int srcl = lg * 16 + (e & 15);
      int carry = e >> 4;
      float s0 = __shfl(bda[0][r], srcl);
      float s1 = __shfl(bda[1][r], srcl);
      float s2 = __shfl(bda[2][r], srcl);
      float s3 = __shfl(bda[3][r], srcl);
      float s4 = __shfl(bda[4][r], srcl);
      p_[0][r] = carry ? s1 : s0;
      p_[1][r] = carry ? s2 : s1;
      p_[2][r] = carry ? s3 : s2;
      p_[3][r] = carry ? s4 : s3;
    }
#pragma unroll
    for (int c = 0; c < 4; ++c) {
      float ukv = ukrow[j0 + c * 16 + lr];
#pragma unroll
      for (int r = 0; r < 4; ++r)
        p_[c][r] = (ac[c][r] + p_[c][r] + ukv) * 0.125f;
    }

#pragma unroll
    for (int r = 0; r < 4; ++r) {
      float lm = fmaxf(fmaxf(p_[0][r], p_[1][r]), fmaxf(p_[2][r], p_[3][r]));
#pragma unroll
      for (int off = 1; off < 16; off <<= 1)
        lm = fmaxf(lm, __shfl_xor(lm, off));
      float mnew = fmaxf(m_run[r], lm);
      float rescale = __expf(m_run[r] - mnew);
      float srow = 0.f;
#pragma unroll
      for (int c = 0; c < 4; ++c) {
        float pe = __expf(p_[c][r] - mnew);
        p_[c][r] = pe;
        srow += pe;
      }
#pragma unroll
      for (int off = 1; off < 16; off <<= 1)
        srow += __shfl_xor(srow, off);
      l_run[r] = l_run[r] * rescale + srow;
      m_run[r] = mnew;
#pragma unroll
      for (int c = 0; c < 4; ++c) pv[c][r] *= rescale;
    }

#pragma unroll
    for (int c = 0; c < 4; ++c)
#pragma unroll
      for (int r = 0; r < 4; ++r) {
        unsigned short th, tl;
        split_bf16(p_[c][r], th, tl);
        Ph[wid * 16 + lg * 4 + r][c * 16 + lr] = th;
        Pl[wid * 16 + lg * 4 + r][c * 16 + lr] = tl;
      }

    // ---- PV MFMAs (V staged for this iter; P wave-private)
    __builtin_amdgcn_s_setprio(1);
#pragma unroll
    for (int ks = 0; ks < 2; ++ks) {
      bf16x8 pah = *(const bf16x8*)&Ph[wid * 16 + lr][ks * 32 + lg * 8];
      bf16x8 pal = *(const bf16x8*)&Pl[wid * 16 + lr][ks * 32 + lg * 8];
#pragma unroll
      for (int c = 0; c < 4; ++c) {
        bf16x8 vbh = *(const bf16x8*)&Vh[c * 16 + lr][ks * 32 + lg * 8];
        bf16x8 vbl = *(const bf16x8*)&Vl[c * 16 + lr][ks * 32 + lg * 8];
        pv[c] = __builtin_amdgcn_mfma_f32_16x16x32_bf16(pah, vbh, pv[c], 0, 0, 0);
        pv[c] = __builtin_amdgcn_mfma_f32_16x16x32_bf16(pah, vbl, pv[c], 0, 0, 0);
        pv[c] = __builtin_amdgcn_mfma_f32_16x16x32_bf16(pal, vbh, pv[c], 0, 0, 0);
      }
    }
    __builtin_amdgcn_s_setprio(0);

    // ---- stage t+1 from prefetch regs, then issue loads for t+2
    if (t < 15) {
      __syncthreads();   // all reads of stage t done
      *(us8v*)&Kh[stj][std8] = rKh;
      *(us8v*)&Kl[stj][std8] = rKl;
      *(us8v*)&Vh[stj][std8] = rVh;
      *(us8v*)&Vl[stj][std8] = rVl;
      { int seg = sbase0 + t + 3;
        int slot = seg % 3;
        *(us8v*)&RWh[slot * 64 + stj][std8] = rRh;
        *(us8v*)&RWl[slot * 64 + stj][std8] = rRl; }
      if (t < 14) LOADKV(t + 2);
      __syncthreads();   // stage t+1 visible
    }
  }
#undef LOADKV

#pragma unroll
  for (int r = 0; r < 4; ++r) {
    float inv = 1.f / l_run[r];
    long base = (long)(b * T_ + q0 + wid * 16 + lg * 4 + r) * 512 + h * 64;
#pragma unroll
    for (int c = 0; c < 4; ++c) {
      unsigned short th, tl;
      split_bf16(pv[c][r] * inv, th, tl);
      oh[base + c * 16 + lr] = th;
      ol[base + c * 16 + lr] = tl;
    }
  }
}

// ---------------------------------------------------------------------------
extern "C" void kernel_launch(void* const* d_in, const int* in_sizes, int n_in,
                              void* d_out, int out_size, void* d_ws, size_t ws_size,
                              hipStream_t stream) {
  const float* x       = (const float*)d_in[0];
  const float* pos_emb = (const float*)d_in[1];
  const float* Wq      = (const float*)d_in[2];
  const float* bq      = (const float*)d_in[3];
  const float* Wk      = (const float*)d_in[4];
  const float* bk      = (const float*)d_in[5];
  const float* Wv      = (const float*)d_in[6];
  const float* bv      = (const float*)d_in[7];
  const float* Wr      = (const float*)d_in[8];
  const float* Wo      = (const float*)d_in[9];
  const float* bo      = (const float*)d_in[10];
  const float* u       = (const float*)d_in[11];
  const float* v       = (const float*)d_in[12];

  float* out = (float*)d_out;
  unsigned short* us = (unsigned short*)d_ws;
  const long S = 2097152;   // MT * D

  unsigned short* qh  = us;
  unsigned short* ql  = us + S;
  unsigned short* kh  = us + 2 * S;
  unsigned short* kl  = us + 3 * S;
  unsigned short* vth = us + 4 * S;
  unsigned short* vtl = us + 5 * S;
  unsigned short* rh  = us + 6 * S;              // 2048*512
  unsigned short* rl  = rh + 1048576;
  unsigned short* xh  = us + 7 * S;              // -> atth after QKV
  unsigned short* xl  = us + 8 * S;
  unsigned short* ph  = us + 9 * S;              // pos split, 2048*512
  unsigned short* pl  = ph + 1048576;
  unsigned short* wth = us + 10 * S;             // 5 x 262144
  unsigned short* wtl = wth + 1310720;
  float* uk = (float*)(wtl + 1310720);           // [4][8][1024]
  float* vr = uk + 32768;                        // [8][2048]

  conv_flat<<<3072, 256, 0, stream>>>(x, xh, xl, pos_emb, ph, pl);
  conv_wt<<<dim3(8, 8, 5), 256, 0, stream>>>(Wq, Wk, Wv, Wr, Wo, wth, wtl);

  EpCfg cq{wth,            wtl,            bq,      nullptr, qh,  ql,  1};
  EpCfg ck{wth + 262144,   wtl + 262144,   bk,      nullptr, kh,  kl,  1};
  EpCfg cv{wth + 524288,   wtl + 524288,   bv,      nullptr, vth, vtl, 2};
  gemm4<<<dim3(32, 24), 256, 0, stream>>>(xh, xl, cq, ck, cv, 4096);

  EpCfg cr{wth + 786432,   wtl + 786432,   nullptr, nullptr, rh,  rl,  1};
  gemm4<<<dim3(16, 8), 256, 0, stream>>>(ph, pl, cr, cr, cr, 2047);

  ukvr_kernel<<<1536, 256, 0, stream>>>(kh, kl, rh, rl, u, v, uk, vr);

  attn_mfma2<<<dim3(8, 8, 4), 512, 0, stream>>>(qh, ql, kh, kl, vth, vtl, rh, rl,
                                                uk, vr, xh, xl);

  EpCfg co{wth + 1048576,  wtl + 1048576,  bo,      out,     nullptr, nullptr, 0};
  gemm4<<<dim3(32, 8), 256, 0, stream>>>(xh, xl, co, co, co, 4096);
}